// Round 7
// baseline (4121.796 us; speedup 1.0000x reference)
//
#include <hip/hip_runtime.h>
#include <hip/hip_bf16.h>

constexpr int kB  = 16;     // batch
constexpr int kN  = 512;    // nodes
constexpr int kH  = 256;    // hidden
constexpr int kH4 = 1024;   // 4*H
constexpr int kV  = 32000;  // vocab
constexpr int kS  = 48;     // MAX_STEPS (steps[b] <= 47)
constexpr int kRB = 64;     // rows per block
constexpr int kNB = kN/kRB; // 8 blocks per example

typedef __attribute__((ext_vector_type(8))) short short8v;  // 8 bf16 = 4 VGPR
typedef __attribute__((ext_vector_type(4))) float f32x4;
typedef unsigned short u16;

__device__ __forceinline__ float sigm(float x){ return 1.f/(1.f+expf(-x)); }

__device__ __forceinline__ u16 f2bf(float f){
  __hip_bfloat16 h = __float2bfloat16(f);
  return __builtin_bit_cast(u16, h);
}
__device__ __forceinline__ float bf2f(u16 u){
  __hip_bfloat16 h = __builtin_bit_cast(__hip_bfloat16, u);
  return __bfloat162float(h);
}

// ---------------- CSR build (deterministic) + barrier reset ----------------
__global__ void k_csr(const int* t_idx, const int* f_idx, int* offsets, int* entries, int* bar){
  int b = blockIdx.x; int t = threadIdx.x; // 512 threads
  if (t == 0) bar[b] = 0;                  // reset persistent-kernel barrier each call
  __shared__ int tl[kN], fl[kN], cnt[kN], pos[kN], ebuf[2*kN];
  tl[t] = t_idx[b*kN+t]; fl[t] = f_idx[b*kN+t];
  cnt[t] = 0;
  __syncthreads();
  atomicAdd(&cnt[tl[t]], 1);
  atomicAdd(&cnt[fl[t]], 1);
  __syncthreads();
  int myc = cnt[t];
  pos[t] = myc;
  __syncthreads();
  for (int off=1; off<kN; off<<=1){
    int v = pos[t];
    int add = (t>=off)? pos[t-off] : 0;
    __syncthreads();
    pos[t] = v + add;
    __syncthreads();
  }
  int excl = pos[t] - myc;
  offsets[b*(kN+1)+t] = excl;
  if (t==0) offsets[b*(kN+1)+kN] = 2*kN;
  __syncthreads();
  pos[t] = excl;
  __syncthreads();
  int p1 = atomicAdd(&pos[tl[t]], 1); ebuf[p1] = t;            // true branch
  int p2 = atomicAdd(&pos[fl[t]], 1); ebuf[p2] = t | (1<<16);  // false branch
  __syncthreads();
  for (int i = excl+1; i < excl+myc; ++i){      // sort own bucket: reference order
    int v = ebuf[i]; int j = i-1;
    while (j >= excl && ebuf[j] > v){ ebuf[j+1] = ebuf[j]; --j; }
    ebuf[j+1] = v;
  }
  __syncthreads();
  entries[b*2*kN + t]      = ebuf[t];
  entries[b*2*kN + kN + t] = ebuf[kN + t];
}

// ---------------- pack both weights into MFMA B-fragment order, split hi/lo ----------------
// frag fi = ((kt*4 + wo)*16 + (g*4+j)); lane l supplies B[k][col] for
// k = kt*32 + (l>>4)*8 + jj, col = g*256 + wo*64 + j*16 + (l&15)
__global__ void k_pack2(const float* __restrict__ Wh, const float* __restrict__ Wx,
                        u16* __restrict__ Whh, u16* __restrict__ Whl,
                        u16* __restrict__ Wxh, u16* __restrict__ Wxl){
  int id = blockIdx.x; int l = threadIdx.x; // 1024 blocks x 64 threads
  const float* W = (id < 512) ? Wh : Wx;
  u16* ph = (id < 512) ? Whh : Wxh;
  u16* pl = (id < 512) ? Whl : Wxl;
  int fi = id & 511;
  int kt = fi >> 6; int wo = (fi>>4)&3; int cfl = fi & 15;
  int g = cfl>>2; int j = cfl&3;
  int col = g*kH + wo*64 + j*16 + (l&15);
  int kb = kt*32 + (l>>4)*8;
  size_t o = (size_t)fi*512 + (size_t)l*8;
  #pragma unroll
  for (int jj=0; jj<8; ++jj){
    float w = W[(size_t)(kb+jj)*kH4 + col];
    u16 hi = f2bf(w);
    u16 lo = f2bf(w - bf2f(hi));
    ph[o+jj] = hi; pl[o+jj] = lo;
  }
}

// ---------------- X = emb @ Wx + bias (MFMA, 3-term), frag-order out; 64-row blocks ----------------
// grid 128 (16 ex x 8 rowblocks of 64), 1024 threads; r-outer keeps VGPR low (B re-read 4x, one-time)
__global__ __launch_bounds__(1024) void k_x_mfma(
    const float* __restrict__ emb,
    const u16* __restrict__ Wxp_hi, const u16* __restrict__ Wxp_lo,
    const float* __restrict__ bias, float* __restrict__ Xp)
{
  int blk = blockIdx.x;
  int b = blk >> 3; int row0 = (blk & 7) * kRB;
  int tid = threadIdx.x;
  int wn = tid >> 6, lane = tid & 63;
  int lrow = lane & 15, lk = lane >> 4;
  int ch = wn*16 + lrow;
  int wo = wn >> 2, jj4 = wn & 3;
  const float* eb_ = emb + ((size_t)b*kN + row0)*kH;
  f32x4* xb = (f32x4*)(Xp + ((size_t)blk*16 + wn)*4096);

  for (int r=0; r<4; ++r){
    f32x4 acc[4];
    #pragma unroll
    for (int g=0;g<4;g++){
      float bv = bias[g*kH + ch];
      acc[g] = (f32x4){bv,bv,bv,bv};
    }
    for (int kt=0; kt<8; ++kt){
      short8v a_hi, a_lo;
      size_t off = (size_t)(r*16+lrow)*kH + kt*32 + lk*8;
      float4 v0 = *(const float4*)(eb_ + off);
      float4 v1 = *(const float4*)(eb_ + off + 4);
      float vv[8] = {v0.x,v0.y,v0.z,v0.w,v1.x,v1.y,v1.z,v1.w};
      #pragma unroll
      for (int q=0;q<8;q++){
        u16 hi = f2bf(vv[q]);
        a_hi[q] = (short)hi;
        a_lo[q] = (short)f2bf(vv[q] - bf2f(hi));
      }
      #pragma unroll
      for (int g=0; g<4; ++g){
        size_t fb = ((size_t)((kt*4+wo)*16 + g*4 + jj4))*512 + (size_t)lane*8;
        short8v bh = *(const short8v*)(Wxp_hi+fb);
        short8v bl = *(const short8v*)(Wxp_lo+fb);
        acc[g] = __builtin_amdgcn_mfma_f32_16x16x32_bf16(a_hi, bh, acc[g], 0,0,0);
        acc[g] = __builtin_amdgcn_mfma_f32_16x16x32_bf16(a_lo, bh, acc[g], 0,0,0);
        acc[g] = __builtin_amdgcn_mfma_f32_16x16x32_bf16(a_hi, bl, acc[g], 0,0,0);
      }
    }
    #pragma unroll
    for (int g=0;g<4;g++)
      xb[(r*4+g)*64 + lane] = acc[g];
  }
}

// ---------------- persistent step loop: per-example 8-block barrier, 64-row blocks ----------------
__global__ __launch_bounds__(1024) void k_persist(
    const float* __restrict__ Xp,
    const u16* __restrict__ Wp_hi,
    const float* __restrict__ Wb, const float* __restrict__ bb,
    const int* __restrict__ exit_idx, const int* __restrict__ steps,
    const int* __restrict__ offsets, const int* __restrict__ entries,
    float* c2a, u16* h2a, float* pta, float* pfa,
    float* c2b, u16* h2b, float* ptb, float* pfb,
    float* exf, int* bar)
{
  int blk = blockIdx.x;
  int b = blk >> 3;
  int row0 = (blk & 7) * kRB;
  int st = steps[b];
  int tid = threadIdx.x;
  int wn = tid >> 6, lane = tid & 63;
  int lrow = lane & 15, lk = lane >> 4;
  int ch = wn*16 + lrow;
  int eb = exit_idx[b];
  int wo = wn >> 2, jj4 = wn & 3;
  float wbc0 = Wb[ch*2+0],      wbc1 = Wb[ch*2+1];
  float wbh0 = Wb[(kH+ch)*2+0], wbh1 = Wb[(kH+ch)*2+1];

  __shared__ u16 hh_lds[kRB*256];     // bf16 h, XOR-swizzled rows (32 KB)
  __shared__ float c_lds[kRB][260];   // gathered c, padded stride (66.6 KB)
  __shared__ float ip_lds[kRB];
  __shared__ float prs[16][kRB][2];

  const int* ebL  = entries + b*2*kN;
  const int* offB = offsets + b*(kN+1);
  int* mybar = &bar[b];
  const f32x4* xb = (const f32x4*)(Xp + ((size_t)blk*16 + wn)*4096);

  for (int s = 0; ; ++s){
    bool fin = (s == st);
    const float* c2r; const u16* h2r; const float* ptr_; const float* pfr;
    float* c2w; u16* h2w; float* ptw; float* pfw;
    if ((s & 1) == 0){ c2r=c2b; h2r=h2b; ptr_=ptb; pfr=pfb; c2w=c2a; h2w=h2a; ptw=pta; pfw=pfa; }
    else             { c2r=c2a; h2r=h2a; ptr_=pta; pfr=pfa; c2w=c2b; h2w=h2b; ptw=ptb; pfw=pfb; }

    // ---- wait for all 8 blocks of this example to finish step s-1 ----
    if (s > 0){
      if (tid == 0){
        while (__hip_atomic_load(mybar, __ATOMIC_ACQUIRE, __HIP_MEMORY_SCOPE_AGENT) < kNB*s)
          __builtin_amdgcn_s_sleep(2);
      }
      __syncthreads();
      __threadfence();   // acquire side: ensure remote writes visible to all threads
    }

    // ---- Phase A: gather previous step's outputs into LDS (or init at s==0) ----
    if (s == 0){
      for (int i = tid; i < kRB*256; i += 1024) hh_lds[i] = 0;
      for (int i = tid; i < kRB*260; i += 1024) (&c_lds[0][0])[i] = 0.f;
      if (tid < kRB) ip_lds[tid] = (row0 + tid == 0) ? 1.f : 0.f;
    } else {
      const float* c2rb = c2r + (size_t)b*kN*kH;
      const u16*   h2rb = h2r + (size_t)b*kN*kH;
      const float* ptb_ = ptr_ + b*kN;
      const float* pfb_ = pfr  + b*kN;
      #pragma unroll
      for (int mi = 0; mi < 4; ++mi){
        int mloc = wn*4 + mi;
        int m = row0 + mloc;
        int start = offB[m], end = offB[m+1];
        float4 aC = {0.f,0.f,0.f,0.f}, aH = {0.f,0.f,0.f,0.f};
        float aP = 0.f;
        for (int e = start; e < end; e += 2){   // batch-2, deterministic order within threshold
          int ent0 = ebL[e];
          bool ok1 = (e+1 < end);
          int ent1 = ebL[ok1 ? e+1 : e];
          int src0 = ent0 & 0xFFFF, src1 = ent1 & 0xFFFF;
          float pv0 = (ent0>>16) ? pfb_[src0] : ptb_[src0];
          float pv1 = (ent1>>16) ? pfb_[src1] : ptb_[src1];
          pv1 = ok1 ? pv1 : 0.f;
          float4  cv0 = *(const float4*)&c2rb[(size_t)src0*kH + lane*4];
          float4  cv1 = *(const float4*)&c2rb[(size_t)src1*kH + lane*4];
          ushort4 hv0 = *(const ushort4*)&h2rb[(size_t)src0*kH + lane*4];
          ushort4 hv1 = *(const ushort4*)&h2rb[(size_t)src1*kH + lane*4];
          aP += pv0 + pv1;
          aC.x += pv0*cv0.x + pv1*cv1.x;
          aC.y += pv0*cv0.y + pv1*cv1.y;
          aC.z += pv0*cv0.z + pv1*cv1.z;
          aC.w += pv0*cv0.w + pv1*cv1.w;
          aH.x += pv0*bf2f(hv0.x) + pv1*bf2f(hv1.x);
          aH.y += pv0*bf2f(hv0.y) + pv1*bf2f(hv1.y);
          aH.z += pv0*bf2f(hv0.z) + pv1*bf2f(hv1.z);
          aH.w += pv0*bf2f(hv0.w) + pv1*bf2f(hv1.w);
        }
        float inv = 1.f/(aP + 1e-7f);
        float oc[4] = {aC.x*inv, aC.y*inv, aC.z*inv, aC.w*inv};
        float oh[4] = {aH.x*inv, aH.y*inv, aH.z*inv, aH.w*inv};
        if (fin){
          if (m == eb){
            *(float4*)&exf[b*2*kH + lane*4]      = *(float4*)oc;
            *(float4*)&exf[b*2*kH + kH + lane*4] = *(float4*)oh;
          }
        } else {
          *(float4*)&c_lds[mloc][lane*4] = *(float4*)oc;
          ushort4 hh4;
          u16* hhp = (u16*)&hh4;
          #pragma unroll
          for (int q=0;q<4;q++) hhp[q] = f2bf(oh[q]);
          int bo2 = (mloc*512 + lane*8) ^ ((mloc&7)<<4);
          *(ushort4*)((char*)hh_lds + bo2) = hh4;
          if (lane == 0) ip_lds[mloc] = aP;
        }
      }
    }
    if (fin) break;   // uniform per block: all threads exit together

    // ---- X accumulator load (overlaps barrier wait of slow waves) ----
    f32x4 acc[4][4];
    #pragma unroll
    for (int r=0;r<4;r++)
      #pragma unroll
      for (int g=0;g<4;g++)
        acc[r][g] = xb[(r*4+g)*64 + lane];
    __syncthreads();

    // ---- Phase B: MFMA K-loop (1-term: bf16 h x bf16-hi W), A from swizzled LDS ----
    for (int kt=0; kt<8; ++kt){
      short8v a[4];
      #pragma unroll
      for (int r=0;r<4;r++){
        int row = r*16 + lrow;
        int bo2 = (row*512 + kt*64 + lk*16) ^ ((row&7)<<4);
        a[r] = *(const short8v*)((char*)hh_lds + bo2);
      }
      #pragma unroll
      for (int g=0; g<4; ++g){
        size_t fb = ((size_t)((kt*4+wo)*16 + g*4 + jj4))*512 + (size_t)lane*8;
        short8v bh = *(const short8v*)(Wp_hi+fb);
        #pragma unroll
        for (int r=0;r<4;r++)
          acc[r][g] = __builtin_amdgcn_mfma_f32_16x16x32_bf16(a[r], bh, acc[r][g], 0,0,0);
      }
    }

    // ---- epilogue: gates, exit override, branch-logit partials ----
    float pr0[16], pr1[16];
    #pragma unroll
    for (int r=0;r<4;r++)
      #pragma unroll
      for (int reg=0;reg<4;reg++){
        int rloc = r*16 + lk*4 + reg;
        int row = row0 + rloc;
        float zi = acc[r][0][reg];
        float zf = acc[r][1][reg];
        float zg = acc[r][2][reg];
        float zo = acc[r][3][reg];
        float cp = c_lds[rloc][ch];
        float c2v = sigm(zf)*cp + sigm(zi)*tanhf(zg);
        float h2v = sigm(zo)*tanhf(c2v);
        if (row == eb){
          int bo2 = (rloc*512 + ch*2) ^ ((rloc&7)<<4);
          c2v = cp;
          h2v = bf2f(*(const u16*)((const char*)hh_lds + bo2));
        }
        size_t gb = ((size_t)b*kN + row)*kH + ch;
        c2w[gb] = c2v;
        h2w[gb] = f2bf(h2v);
        int pi = r*4+reg;
        pr0[pi] = c2v*wbc0 + h2v*wbh0;
        pr1[pi] = c2v*wbc1 + h2v*wbh1;
      }

    #pragma unroll
    for (int off=1; off<16; off<<=1){
      #pragma unroll
      for (int i=0;i<16;i++){
        pr0[i] += __shfl_xor(pr0[i], off);
        pr1[i] += __shfl_xor(pr1[i], off);
      }
    }
    if (lrow == 0){
      #pragma unroll
      for (int r=0;r<4;r++)
        #pragma unroll
        for (int reg=0;reg<4;reg++){
          int lr = r*16 + lk*4 + reg;
          prs[wn][lr][0] = pr0[r*4+reg];
          prs[wn][lr][1] = pr1[r*4+reg];
        }
    }
    __syncthreads();
    if (tid < kRB){
      int row = row0 + tid;
      float u0 = bb[0], u1 = bb[1];
      #pragma unroll
      for (int w=0;w<16;w++){ u0 += prs[w][tid][0]; u1 += prs[w][tid][1]; }
      float mx = fmaxf(u0,u1);
      float e0 = expf(u0-mx), e1 = expf(u1-mx);
      float inv = 1.f/(e0+e1);
      float ipv = ip_lds[tid];
      ptw[b*kN+row] = (e0*inv)*ipv;
      pfw[b*kN+row] = (e1*inv)*ipv;
    }

    // ---- arrive: publish this block's step-s outputs ----
    __threadfence();
    __syncthreads();
    if (tid == 0)
      __hip_atomic_fetch_add(mybar, 1, __ATOMIC_RELEASE, __HIP_MEMORY_SCOPE_AGENT);
  }
}

// ---------------- final: logits = exitstate @ Wo + bo  (split-K) ----------------
__global__ __launch_bounds__(256) void k_out_part(
    const float* __restrict__ exf, const float* __restrict__ Wo,
    float* __restrict__ partial)
{
  int kq = blockIdx.x / 125;
  int vt = blockIdx.x % 125;
  int t = threadIdx.x;
  __shared__ float sf[kB][128];
  for (int i = t; i < kB*128; i += 256){
    int b = i >> 7; int kl = i & 127;
    sf[b][kl] = exf[b*2*kH + kq*128 + kl];
  }
  __syncthreads();
  int v = vt*256 + t;
  float acc[kB];
  #pragma unroll
  for (int b=0;b<kB;b++) acc[b] = 0.f;
  int k0 = kq*128;
  for (int kl=0; kl<128; kl+=4){
    float w0 = Wo[(size_t)(k0+kl+0)*kV + v];
    float w1 = Wo[(size_t)(k0+kl+1)*kV + v];
    float w2 = Wo[(size_t)(k0+kl+2)*kV + v];
    float w3 = Wo[(size_t)(k0+kl+3)*kV + v];
    #pragma unroll
    for (int b=0;b<kB;b++){
      float4 s4 = *(const float4*)&sf[b][kl];
      acc[b] += s4.x*w0 + s4.y*w1 + s4.z*w2 + s4.w*w3;
    }
  }
  #pragma unroll
  for (int b=0;b<kB;b++) partial[(size_t)(kq*kB+b)*kV + v] = acc[b];
}

__global__ __launch_bounds__(256) void k_out_sum(
    const float* __restrict__ partial, const float* __restrict__ bo,
    float* __restrict__ out)
{
  int v = blockIdx.x*256 + threadIdx.x;
  if (v >= kV) return;
  float bv = bo[v];
  #pragma unroll
  for (int b=0;b<kB;b++){
    float s = bv;
    #pragma unroll
    for (int q=0;q<4;q++) s += partial[(size_t)(q*kB+b)*kV + v];
    out[(size_t)b*kV + v] = s;
  }
}

extern "C" void kernel_launch(void* const* d_in, const int* in_sizes, int n_in,
                              void* d_out, int out_size, void* d_ws, size_t ws_size,
                              hipStream_t stream) {
  const float* emb   = (const float*)d_in[0];
  const float* Wx    = (const float*)d_in[1];
  const float* Wh    = (const float*)d_in[2];
  const float* bias  = (const float*)d_in[3];
  const float* Wb    = (const float*)d_in[4];
  const float* bbias = (const float*)d_in[5];
  const float* Wo    = (const float*)d_in[6];
  const float* bo    = (const float*)d_in[7];
  const int* t_idx   = (const int*)d_in[8];
  const int* f_idx   = (const int*)d_in[9];
  const int* exit_i  = (const int*)d_in[10];
  const int* steps   = (const int*)d_in[11];
  float* out = (float*)d_out;

  char* ws = (char*)d_ws;
  float* Xp  = (float*)ws; ws += (size_t)kB*kN*kH4*4;     // 33.55 MB, fragment-ordered X
  float* c2a = (float*)ws; ws += (size_t)kB*kN*kH*4;      // ping (written at even s)
  float* c2b = (float*)ws; ws += (size_t)kB*kN*kH*4;      // pong (written at odd s)
  u16* h2a = (u16*)ws;    ws += (size_t)kB*kN*kH*2;       // bf16 h state
  u16* h2b = (u16*)ws;    ws += (size_t)kB*kN*kH*2;
  u16* Wp_hi  = (u16*)ws; ws += (size_t)kH*kH4*2;
  u16* Wp_lo  = (u16*)ws; ws += (size_t)kH*kH4*2;         // packed but unused in step loop
  u16* Wxp_hi = (u16*)ws; ws += (size_t)kH*kH4*2;
  u16* Wxp_lo = (u16*)ws; ws += (size_t)kH*kH4*2;
  float* pta = (float*)ws; ws += (size_t)kB*kN*4;
  float* pfa = (float*)ws; ws += (size_t)kB*kN*4;
  float* ptb = (float*)ws; ws += (size_t)kB*kN*4;
  float* pfb = (float*)ws; ws += (size_t)kB*kN*4;
  float* exf = (float*)ws; ws += (size_t)kB*2*kH*4;
  int* offsets = (int*)ws; ws += ((size_t)kB*(kN+1)*4 + 255) & ~(size_t)255;
  int* entries = (int*)ws; ws += (size_t)kB*2*kN*4;
  int* bar     = (int*)ws; ws += 256;
  float* partial = Xp;  // reused after the step loop

  k_csr<<<kB, kN, 0, stream>>>(t_idx, f_idx, offsets, entries, bar);
  k_pack2<<<1024, 64, 0, stream>>>(Wh, Wx, Wp_hi, Wp_lo, Wxp_hi, Wxp_lo);
  k_x_mfma<<<128, 1024, 0, stream>>>(emb, Wxp_hi, Wxp_lo, bias, Xp);

  k_persist<<<128, 1024, 0, stream>>>(
      Xp, Wp_hi, Wb, bbias, exit_i, steps, offsets, entries,
      c2a, h2a, pta, pfa, c2b, h2b, ptb, pfb, exf, bar);

  k_out_part<<<500, 256, 0, stream>>>(exf, Wo, partial);
  k_out_sum<<<125, 256, 0, stream>>>(partial, bo, out);
}

// Round 8
// 1669.000 us; speedup vs baseline: 2.4696x; 2.4696x over previous
//
#include <hip/hip_runtime.h>
#include <hip/hip_bf16.h>

constexpr int kB  = 16;     // batch
constexpr int kN  = 512;    // nodes
constexpr int kH  = 256;    // hidden
constexpr int kH4 = 1024;   // 4*H
constexpr int kV  = 32000;  // vocab
constexpr int kS  = 48;     // MAX_STEPS (steps[b] <= 47)
constexpr int kRB = 64;     // rows per block
constexpr int kNB = kN/kRB; // 8 blocks per example

typedef __attribute__((ext_vector_type(8))) short short8v;  // 8 bf16 = 4 VGPR
typedef __attribute__((ext_vector_type(4))) float f32x4;
typedef unsigned short u16;

__device__ __forceinline__ float sigm(float x){ return 1.f/(1.f+expf(-x)); }

__device__ __forceinline__ u16 f2bf(float f){
  __hip_bfloat16 h = __float2bfloat16(f);
  return __builtin_bit_cast(u16, h);
}
__device__ __forceinline__ float bf2f(u16 u){
  __hip_bfloat16 h = __builtin_bit_cast(__hip_bfloat16, u);
  return __bfloat162float(h);
}

// ---------------- CSR build (deterministic): atomics for counts/placement + bucket sort ----------------
__global__ void k_csr(const int* t_idx, const int* f_idx, int* offsets, int* entries){
  int b = blockIdx.x; int t = threadIdx.x; // 512 threads
  __shared__ int tl[kN], fl[kN], cnt[kN], pos[kN], ebuf[2*kN];
  tl[t] = t_idx[b*kN+t]; fl[t] = f_idx[b*kN+t];
  cnt[t] = 0;
  __syncthreads();
  atomicAdd(&cnt[tl[t]], 1);
  atomicAdd(&cnt[fl[t]], 1);
  __syncthreads();
  int myc = cnt[t];
  pos[t] = myc;
  __syncthreads();
  for (int off=1; off<kN; off<<=1){
    int v = pos[t];
    int add = (t>=off)? pos[t-off] : 0;
    __syncthreads();
    pos[t] = v + add;
    __syncthreads();
  }
  int excl = pos[t] - myc;
  offsets[b*(kN+1)+t] = excl;
  if (t==0) offsets[b*(kN+1)+kN] = 2*kN;
  __syncthreads();
  pos[t] = excl;
  __syncthreads();
  int p1 = atomicAdd(&pos[tl[t]], 1); ebuf[p1] = t;            // true branch
  int p2 = atomicAdd(&pos[fl[t]], 1); ebuf[p2] = t | (1<<16);  // false branch
  __syncthreads();
  for (int i = excl+1; i < excl+myc; ++i){      // sort own bucket: reference order
    int v = ebuf[i]; int j = i-1;
    while (j >= excl && ebuf[j] > v){ ebuf[j+1] = ebuf[j]; --j; }
    ebuf[j+1] = v;
  }
  __syncthreads();
  entries[b*2*kN + t]      = ebuf[t];
  entries[b*2*kN + kN + t] = ebuf[kN + t];
}

// ---------------- pack both weights into MFMA B-fragment order, split hi/lo ----------------
// frag fi = ((kt*4 + wo)*16 + (g*4+j)); lane l supplies B[k][col] for
// k = kt*32 + (l>>4)*8 + jj, col = g*256 + wo*64 + j*16 + (l&15)
__global__ void k_pack2(const float* __restrict__ Wh, const float* __restrict__ Wx,
                        u16* __restrict__ Whh, u16* __restrict__ Whl,
                        u16* __restrict__ Wxh, u16* __restrict__ Wxl){
  int id = blockIdx.x; int l = threadIdx.x; // 1024 blocks x 64 threads
  const float* W = (id < 512) ? Wh : Wx;
  u16* ph = (id < 512) ? Whh : Wxh;
  u16* pl = (id < 512) ? Whl : Wxl;
  int fi = id & 511;
  int kt = fi >> 6; int wo = (fi>>4)&3; int cfl = fi & 15;
  int g = cfl>>2; int j = cfl&3;
  int col = g*kH + wo*64 + j*16 + (l&15);
  int kb = kt*32 + (l>>4)*8;
  size_t o = (size_t)fi*512 + (size_t)l*8;
  #pragma unroll
  for (int jj=0; jj<8; ++jj){
    float w = W[(size_t)(kb+jj)*kH4 + col];
    u16 hi = f2bf(w);
    u16 lo = f2bf(w - bf2f(hi));
    ph[o+jj] = hi; pl[o+jj] = lo;
  }
}

// ---------------- X = emb @ Wx + bias (MFMA, 3-term), frag-order out; 64-row blocks ----------------
// grid 128 (16 ex x 8 rowblocks of 64), 1024 threads; r-outer keeps VGPR low
__global__ __launch_bounds__(1024) void k_x_mfma(
    const float* __restrict__ emb,
    const u16* __restrict__ Wxp_hi, const u16* __restrict__ Wxp_lo,
    const float* __restrict__ bias, float* __restrict__ Xp)
{
  int blk = blockIdx.x;
  int b = blk >> 3; int row0 = (blk & 7) * kRB;
  int tid = threadIdx.x;
  int wn = tid >> 6, lane = tid & 63;
  int lrow = lane & 15, lk = lane >> 4;
  int ch = wn*16 + lrow;
  int wo = wn >> 2, jj4 = wn & 3;
  const float* eb_ = emb + ((size_t)b*kN + row0)*kH;
  f32x4* xb = (f32x4*)(Xp + ((size_t)blk*16 + wn)*4096);

  for (int r=0; r<4; ++r){
    f32x4 acc[4];
    #pragma unroll
    for (int g=0;g<4;g++){
      float bv = bias[g*kH + ch];
      acc[g] = (f32x4){bv,bv,bv,bv};
    }
    for (int kt=0; kt<8; ++kt){
      short8v a_hi, a_lo;
      size_t off = (size_t)(r*16+lrow)*kH + kt*32 + lk*8;
      float4 v0 = *(const float4*)(eb_ + off);
      float4 v1 = *(const float4*)(eb_ + off + 4);
      float vv[8] = {v0.x,v0.y,v0.z,v0.w,v1.x,v1.y,v1.z,v1.w};
      #pragma unroll
      for (int q=0;q<8;q++){
        u16 hi = f2bf(vv[q]);
        a_hi[q] = (short)hi;
        a_lo[q] = (short)f2bf(vv[q] - bf2f(hi));
      }
      #pragma unroll
      for (int g=0; g<4; ++g){
        size_t fb = ((size_t)((kt*4+wo)*16 + g*4 + jj4))*512 + (size_t)lane*8;
        short8v bh = *(const short8v*)(Wxp_hi+fb);
        short8v bl = *(const short8v*)(Wxp_lo+fb);
        acc[g] = __builtin_amdgcn_mfma_f32_16x16x32_bf16(a_hi, bh, acc[g], 0,0,0);
        acc[g] = __builtin_amdgcn_mfma_f32_16x16x32_bf16(a_lo, bh, acc[g], 0,0,0);
        acc[g] = __builtin_amdgcn_mfma_f32_16x16x32_bf16(a_hi, bl, acc[g], 0,0,0);
      }
    }
    #pragma unroll
    for (int g=0;g<4;g++)
      xb[(r*4+g)*64 + lane] = acc[g];
  }
}

// ---------------- fused step (per-launch): gather(s-1) + LSTM/branch(s); 64-row blocks ----------------
// grid 128 blocks (16 ex x 8 rowblocks of 64), 1024 threads = 16 waves.
__global__ __launch_bounds__(1024) void k_fused64(
    const float* __restrict__ Xp,
    const u16* __restrict__ Wp_hi,
    const float* __restrict__ Wb, const float* __restrict__ bb,
    const int* __restrict__ exit_idx, const int* __restrict__ steps,
    const int* __restrict__ offsets, const int* __restrict__ entries,
    const float* __restrict__ c2r, const u16* __restrict__ h2r,
    const float* __restrict__ ptr_, const float* __restrict__ pfr,
    float* __restrict__ c2w, u16* __restrict__ h2w,
    float* __restrict__ ptw, float* __restrict__ pfw,
    float* __restrict__ exf, int s)
{
  int blk = blockIdx.x;
  int b = blk >> 3;
  int st = steps[b];
  if (s > st) return;
  int row0 = (blk & 7) * kRB;
  int tid = threadIdx.x;
  int wn = tid >> 6, lane = tid & 63;
  int lrow = lane & 15, lk = lane >> 4;
  int ch = wn*16 + lrow;
  int eb = exit_idx[b];
  int wo = wn >> 2, jj4 = wn & 3;
  bool fin = (s == st);

  __shared__ u16 hh_lds[kRB*256];     // bf16 h, XOR-swizzled rows (32 KB)
  __shared__ float c_lds[kRB][260];   // gathered c, padded stride (66.6 KB)
  __shared__ float ip_lds[kRB];
  __shared__ float prs[16][kRB][2];

  // issue X loads early (independent of gather)
  f32x4 acc[4][4];
  if (!fin){
    const f32x4* xb = (const f32x4*)(Xp + ((size_t)blk*16 + wn)*4096);
    #pragma unroll
    for (int r=0;r<4;r++)
      #pragma unroll
      for (int g=0;g<4;g++)
        acc[r][g] = xb[(r*4+g)*64 + lane];
  }

  // ---- Phase A: gather previous step's outputs into LDS (or init at s==0) ----
  if (s == 0){
    for (int i = tid; i < kRB*256; i += 1024) hh_lds[i] = 0;
    for (int i = tid; i < kRB*260; i += 1024) (&c_lds[0][0])[i] = 0.f;
    if (tid < kRB) ip_lds[tid] = (row0 + tid == 0) ? 1.f : 0.f;
  } else {
    const float* c2rb = c2r + (size_t)b*kN*kH;
    const u16*   h2rb = h2r + (size_t)b*kN*kH;
    const int*   ebL  = entries + b*2*kN;
    const int*   offB = offsets + b*(kN+1);
    const float* ptb_ = ptr_ + b*kN;
    const float* pfb_ = pfr  + b*kN;
    #pragma unroll
    for (int mi = 0; mi < 4; ++mi){
      int mloc = wn*4 + mi;
      int m = row0 + mloc;
      if (fin && m != eb) continue;      // final step: only the exit row matters
      int start = offB[m], end = offB[m+1];
      float4 aC = {0.f,0.f,0.f,0.f}, aH = {0.f,0.f,0.f,0.f};
      float aP = 0.f;
      for (int e = start; e < end; e += 2){   // batch-2, deterministic order
        int ent0 = ebL[e];
        bool ok1 = (e+1 < end);
        int ent1 = ebL[ok1 ? e+1 : e];
        int src0 = ent0 & 0xFFFF, src1 = ent1 & 0xFFFF;
        float pv0 = (ent0>>16) ? pfb_[src0] : ptb_[src0];
        float pv1 = (ent1>>16) ? pfb_[src1] : ptb_[src1];
        pv1 = ok1 ? pv1 : 0.f;
        float4  cv0 = *(const float4*)&c2rb[(size_t)src0*kH + lane*4];
        float4  cv1 = *(const float4*)&c2rb[(size_t)src1*kH + lane*4];
        ushort4 hv0 = *(const ushort4*)&h2rb[(size_t)src0*kH + lane*4];
        ushort4 hv1 = *(const ushort4*)&h2rb[(size_t)src1*kH + lane*4];
        aP += pv0 + pv1;
        aC.x += pv0*cv0.x + pv1*cv1.x;
        aC.y += pv0*cv0.y + pv1*cv1.y;
        aC.z += pv0*cv0.z + pv1*cv1.z;
        aC.w += pv0*cv0.w + pv1*cv1.w;
        aH.x += pv0*bf2f(hv0.x) + pv1*bf2f(hv1.x);
        aH.y += pv0*bf2f(hv0.y) + pv1*bf2f(hv1.y);
        aH.z += pv0*bf2f(hv0.z) + pv1*bf2f(hv1.z);
        aH.w += pv0*bf2f(hv0.w) + pv1*bf2f(hv1.w);
      }
      float inv = 1.f/(aP + 1e-7f);
      float oc[4] = {aC.x*inv, aC.y*inv, aC.z*inv, aC.w*inv};
      float oh[4] = {aH.x*inv, aH.y*inv, aH.z*inv, aH.w*inv};
      if (fin){
        *(float4*)&exf[b*2*kH + lane*4]      = *(float4*)oc;
        *(float4*)&exf[b*2*kH + kH + lane*4] = *(float4*)oh;
      } else {
        *(float4*)&c_lds[mloc][lane*4] = *(float4*)oc;
        ushort4 hh4;
        u16* hhp = (u16*)&hh4;
        #pragma unroll
        for (int q=0;q<4;q++) hhp[q] = f2bf(oh[q]);
        int bo2 = (mloc*512 + lane*8) ^ ((mloc&7)<<4);
        *(ushort4*)((char*)hh_lds + bo2) = hh4;
        if (lane == 0) ip_lds[mloc] = aP;
      }
    }
  }
  if (fin) return;
  __syncthreads();

  // ---- Phase B: MFMA K-loop (1-term: bf16 h x bf16-hi W), A from swizzled LDS ----
  for (int kt=0; kt<8; ++kt){
    short8v a[4];
    #pragma unroll
    for (int r=0;r<4;r++){
      int row = r*16 + lrow;
      int bo2 = (row*512 + kt*64 + lk*16) ^ ((row&7)<<4);
      a[r] = *(const short8v*)((char*)hh_lds + bo2);
    }
    #pragma unroll
    for (int g=0; g<4; ++g){
      size_t fb = ((size_t)((kt*4+wo)*16 + g*4 + jj4))*512 + (size_t)lane*8;
      short8v bh = *(const short8v*)(Wp_hi+fb);
      #pragma unroll
      for (int r=0;r<4;r++)
        acc[r][g] = __builtin_amdgcn_mfma_f32_16x16x32_bf16(a[r], bh, acc[r][g], 0,0,0);
    }
  }

  // ---- epilogue: gates, exit override, branch-logit partials ----
  float wbc0 = Wb[ch*2+0],      wbc1 = Wb[ch*2+1];
  float wbh0 = Wb[(kH+ch)*2+0], wbh1 = Wb[(kH+ch)*2+1];
  float pr0[16], pr1[16];
  #pragma unroll
  for (int r=0;r<4;r++)
    #pragma unroll
    for (int reg=0;reg<4;reg++){
      int rloc = r*16 + lk*4 + reg;
      int row = row0 + rloc;
      float zi = acc[r][0][reg];
      float zf = acc[r][1][reg];
      float zg = acc[r][2][reg];
      float zo = acc[r][3][reg];
      float cp = c_lds[rloc][ch];
      float c2v = sigm(zf)*cp + sigm(zi)*tanhf(zg);
      float h2v = sigm(zo)*tanhf(c2v);
      if (row == eb){
        int bo2 = (rloc*512 + ch*2) ^ ((rloc&7)<<4);
        c2v = cp;
        h2v = bf2f(*(const u16*)((const char*)hh_lds + bo2));
      }
      size_t gb = ((size_t)b*kN + row)*kH + ch;
      c2w[gb] = c2v;
      h2w[gb] = f2bf(h2v);
      int pi = r*4+reg;
      pr0[pi] = c2v*wbc0 + h2v*wbh0;
      pr1[pi] = c2v*wbc1 + h2v*wbh1;
    }

  #pragma unroll
  for (int off=1; off<16; off<<=1){
    #pragma unroll
    for (int i=0;i<16;i++){
      pr0[i] += __shfl_xor(pr0[i], off);
      pr1[i] += __shfl_xor(pr1[i], off);
    }
  }
  if (lrow == 0){
    #pragma unroll
    for (int r=0;r<4;r++)
      #pragma unroll
      for (int reg=0;reg<4;reg++){
        int lr = r*16 + lk*4 + reg;
        prs[wn][lr][0] = pr0[r*4+reg];
        prs[wn][lr][1] = pr1[r*4+reg];
      }
  }
  __syncthreads();
  if (tid < kRB){
    int row = row0 + tid;
    float u0 = bb[0], u1 = bb[1];
    #pragma unroll
    for (int w=0;w<16;w++){ u0 += prs[w][tid][0]; u1 += prs[w][tid][1]; }
    float mx = fmaxf(u0,u1);
    float e0 = expf(u0-mx), e1 = expf(u1-mx);
    float inv = 1.f/(e0+e1);
    float ipv = ip_lds[tid];
    ptw[b*kN+row] = (e0*inv)*ipv;
    pfw[b*kN+row] = (e1*inv)*ipv;
  }
}

// ---------------- final: logits = exitstate @ Wo + bo  (split-K) ----------------
__global__ __launch_bounds__(256) void k_out_part(
    const float* __restrict__ exf, const float* __restrict__ Wo,
    float* __restrict__ partial)
{
  int kq = blockIdx.x / 125;
  int vt = blockIdx.x % 125;
  int t = threadIdx.x;
  __shared__ float sf[kB][128];
  for (int i = t; i < kB*128; i += 256){
    int b = i >> 7; int kl = i & 127;
    sf[b][kl] = exf[b*2*kH + kq*128 + kl];
  }
  __syncthreads();
  int v = vt*256 + t;
  float acc[kB];
  #pragma unroll
  for (int b=0;b<kB;b++) acc[b] = 0.f;
  int k0 = kq*128;
  for (int kl=0; kl<128; kl+=4){
    float w0 = Wo[(size_t)(k0+kl+0)*kV + v];
    float w1 = Wo[(size_t)(k0+kl+1)*kV + v];
    float w2 = Wo[(size_t)(k0+kl+2)*kV + v];
    float w3 = Wo[(size_t)(k0+kl+3)*kV + v];
    #pragma unroll
    for (int b=0;b<kB;b++){
      float4 s4 = *(const float4*)&sf[b][kl];
      acc[b] += s4.x*w0 + s4.y*w1 + s4.z*w2 + s4.w*w3;
    }
  }
  #pragma unroll
  for (int b=0;b<kB;b++) partial[(size_t)(kq*kB+b)*kV + v] = acc[b];
}

__global__ __launch_bounds__(256) void k_out_sum(
    const float* __restrict__ partial, const float* __restrict__ bo,
    float* __restrict__ out)
{
  int v = blockIdx.x*256 + threadIdx.x;
  if (v >= kV) return;
  float bv = bo[v];
  #pragma unroll
  for (int b=0;b<kB;b++){
    float s = bv;
    #pragma unroll
    for (int q=0;q<4;q++) s += partial[(size_t)(q*kB+b)*kV + v];
    out[(size_t)b*kV + v] = s;
  }
}

extern "C" void kernel_launch(void* const* d_in, const int* in_sizes, int n_in,
                              void* d_out, int out_size, void* d_ws, size_t ws_size,
                              hipStream_t stream) {
  const float* emb   = (const float*)d_in[0];
  const float* Wx    = (const float*)d_in[1];
  const float* Wh    = (const float*)d_in[2];
  const float* bias  = (const float*)d_in[3];
  const float* Wb    = (const float*)d_in[4];
  const float* bbias = (const float*)d_in[5];
  const float* Wo    = (const float*)d_in[6];
  const float* bo    = (const float*)d_in[7];
  const int* t_idx   = (const int*)d_in[8];
  const int* f_idx   = (const int*)d_in[9];
  const int* exit_i  = (const int*)d_in[10];
  const int* steps   = (const int*)d_in[11];
  float* out = (float*)d_out;

  char* ws = (char*)d_ws;
  float* Xp  = (float*)ws; ws += (size_t)kB*kN*kH4*4;     // 33.55 MB, fragment-ordered X
  float* c2a = (float*)ws; ws += (size_t)kB*kN*kH*4;      // ping (written at even s)
  float* c2b = (float*)ws; ws += (size_t)kB*kN*kH*4;      // pong (written at odd s)
  u16* h2a = (u16*)ws;    ws += (size_t)kB*kN*kH*2;       // bf16 h state
  u16* h2b = (u16*)ws;    ws += (size_t)kB*kN*kH*2;
  u16* Wp_hi  = (u16*)ws; ws += (size_t)kH*kH4*2;
  u16* Wp_lo  = (u16*)ws; ws += (size_t)kH*kH4*2;         // packed but unused in step loop
  u16* Wxp_hi = (u16*)ws; ws += (size_t)kH*kH4*2;
  u16* Wxp_lo = (u16*)ws; ws += (size_t)kH*kH4*2;
  float* pta = (float*)ws; ws += (size_t)kB*kN*4;
  float* pfa = (float*)ws; ws += (size_t)kB*kN*4;
  float* ptb = (float*)ws; ws += (size_t)kB*kN*4;
  float* pfb = (float*)ws; ws += (size_t)kB*kN*4;
  float* exf = (float*)ws; ws += (size_t)kB*2*kH*4;
  int* offsets = (int*)ws; ws += ((size_t)kB*(kN+1)*4 + 255) & ~(size_t)255;
  int* entries = (int*)ws; ws += (size_t)kB*2*kN*4;
  float* partial = Xp;  // reused after the step loop

  k_csr<<<kB, kN, 0, stream>>>(t_idx, f_idx, offsets, entries);
  k_pack2<<<1024, 64, 0, stream>>>(Wh, Wx, Wp_hi, Wp_lo, Wxp_hi, Wxp_lo);
  k_x_mfma<<<128, 1024, 0, stream>>>(emb, Wxp_hi, Wxp_lo, bias, Xp);

  for (int s = 0; s < kS; ++s){
    bool even = ((s & 1) == 0);
    k_fused64<<<128, 1024, 0, stream>>>(
        Xp, Wp_hi, Wb, bbias, exit_i, steps, offsets, entries,
        even ? c2b : c2a, even ? h2b : h2a, even ? ptb : pta, even ? pfb : pfa,  // read (s-1)
        even ? c2a : c2b, even ? h2a : h2b, even ? pta : ptb, even ? pfa : pfb,  // write (s)
        exf, s);
  }

  k_out_part<<<500, 256, 0, stream>>>(exf, Wo, partial);
  k_out_sum<<<125, 256, 0, stream>>>(partial, bo, out);
}

// Round 9
// 1026.992 us; speedup vs baseline: 4.0135x; 1.6251x over previous
//
#include <hip/hip_runtime.h>
#include <hip/hip_bf16.h>

constexpr int kB  = 16;     // batch
constexpr int kN  = 512;    // nodes
constexpr int kH  = 256;    // hidden
constexpr int kH4 = 1024;   // 4*H
constexpr int kV  = 32000;  // vocab
constexpr int kS  = 48;     // MAX_STEPS (steps[b] <= 47)

typedef __attribute__((ext_vector_type(8))) short short8v;  // 8 bf16 = 4 VGPR
typedef __attribute__((ext_vector_type(4))) float f32x4;
typedef unsigned short u16;

__device__ __forceinline__ float sigm(float x){ return 1.f/(1.f+expf(-x)); }

__device__ __forceinline__ u16 f2bf(float f){
  __hip_bfloat16 h = __float2bfloat16(f);
  return __builtin_bit_cast(u16, h);
}
__device__ __forceinline__ float bf2f(u16 u){
  __hip_bfloat16 h = __builtin_bit_cast(__hip_bfloat16, u);
  return __bfloat162float(h);
}

// ---------------- CSR build (deterministic): atomics for counts/placement + bucket sort ----------------
__global__ void k_csr(const int* t_idx, const int* f_idx, int* offsets, int* entries){
  int b = blockIdx.x; int t = threadIdx.x; // 512 threads
  __shared__ int tl[kN], fl[kN], cnt[kN], pos[kN], ebuf[2*kN];
  tl[t] = t_idx[b*kN+t]; fl[t] = f_idx[b*kN+t];
  cnt[t] = 0;
  __syncthreads();
  atomicAdd(&cnt[tl[t]], 1);
  atomicAdd(&cnt[fl[t]], 1);
  __syncthreads();
  int myc = cnt[t];
  pos[t] = myc;
  __syncthreads();
  for (int off=1; off<kN; off<<=1){
    int v = pos[t];
    int add = (t>=off)? pos[t-off] : 0;
    __syncthreads();
    pos[t] = v + add;
    __syncthreads();
  }
  int excl = pos[t] - myc;
  offsets[b*(kN+1)+t] = excl;
  if (t==0) offsets[b*(kN+1)+kN] = 2*kN;
  __syncthreads();
  pos[t] = excl;
  __syncthreads();
  int p1 = atomicAdd(&pos[tl[t]], 1); ebuf[p1] = t;            // true branch
  int p2 = atomicAdd(&pos[fl[t]], 1); ebuf[p2] = t | (1<<16);  // false branch
  __syncthreads();
  for (int i = excl+1; i < excl+myc; ++i){      // sort own bucket: reference order
    int v = ebuf[i]; int j = i-1;
    while (j >= excl && ebuf[j] > v){ ebuf[j+1] = ebuf[j]; --j; }
    ebuf[j+1] = v;
  }
  __syncthreads();
  entries[b*2*kN + t]      = ebuf[t];
  entries[b*2*kN + kN + t] = ebuf[kN + t];
}

// ---------------- pack weights into MFMA B-fragment order (Wh: hi only; Wx: hi+lo) ----------------
// frag fi = ((kt*4 + wo)*16 + (g*4+j)); lane l supplies B[k][col] for
// k = kt*32 + (l>>4)*8 + jj, col = g*256 + wo*64 + j*16 + (l&15)
__global__ void k_pack2(const float* __restrict__ Wh, const float* __restrict__ Wx,
                        u16* __restrict__ Whh,
                        u16* __restrict__ Wxh, u16* __restrict__ Wxl){
  int id = blockIdx.x; int l = threadIdx.x; // 1024 blocks x 64 threads
  bool isWh = (id < 512);
  const float* W = isWh ? Wh : Wx;
  u16* ph = isWh ? Whh : Wxh;
  int fi = id & 511;
  int kt = fi >> 6; int wo = (fi>>4)&3; int cfl = fi & 15;
  int g = cfl>>2; int j = cfl&3;
  int col = g*kH + wo*64 + j*16 + (l&15);
  int kb = kt*32 + (l>>4)*8;
  size_t o = (size_t)fi*512 + (size_t)l*8;
  #pragma unroll
  for (int jj=0; jj<8; ++jj){
    float w = W[(size_t)(kb+jj)*kH4 + col];
    u16 hi = f2bf(w);
    ph[o+jj] = hi;
    if (!isWh) Wxl[o+jj] = f2bf(w - bf2f(hi));
  }
}

// ---------------- X = emb @ Wx + bias (MFMA, 3-term), bf16 frag-order out; 32-row blocks ----------------
// grid 256 (16 ex x 16 rowblocks of 32), 1024 threads = 16 waves.
__global__ __launch_bounds__(1024) void k_x_mfma(
    const float* __restrict__ emb,
    const u16* __restrict__ Wxp_hi, const u16* __restrict__ Wxp_lo,
    const float* __restrict__ bias, u16* __restrict__ Xp)
{
  int blk = blockIdx.x;
  int b = blk >> 4; int row0 = (blk & 15) * 32;
  int tid = threadIdx.x;
  int wn = tid >> 6, lane = tid & 63;
  int lrow = lane & 15, lk = lane >> 4;
  int ch = wn*16 + lrow;

  f32x4 acc[2][4];
  #pragma unroll
  for (int r=0;r<2;r++)
    #pragma unroll
    for (int g=0;g<4;g++){
      float bv = bias[g*kH + ch];
      acc[r][g] = (f32x4){bv,bv,bv,bv};
    }

  const float* eb_ = emb + ((size_t)b*kN + row0)*kH;
  int wo = wn >> 2, jj4 = wn & 3;
  for (int kt=0; kt<8; ++kt){
    short8v a_hi[2], a_lo[2];
    #pragma unroll
    for (int r=0;r<2;r++){
      size_t off = (size_t)(r*16+lrow)*kH + kt*32 + lk*8;
      float4 v0 = *(const float4*)(eb_ + off);
      float4 v1 = *(const float4*)(eb_ + off + 4);
      float vv[8] = {v0.x,v0.y,v0.z,v0.w,v1.x,v1.y,v1.z,v1.w};
      #pragma unroll
      for (int q=0;q<8;q++){
        u16 hi = f2bf(vv[q]);
        a_hi[r][q] = (short)hi;
        a_lo[r][q] = (short)f2bf(vv[q] - bf2f(hi));
      }
    }
    #pragma unroll
    for (int g=0; g<4; ++g){
      size_t fb = ((size_t)((kt*4+wo)*16 + g*4 + jj4))*512 + (size_t)lane*8;
      short8v bh = *(const short8v*)(Wxp_hi+fb);
      short8v bl = *(const short8v*)(Wxp_lo+fb);
      #pragma unroll
      for (int r=0;r<2;r++){
        acc[r][g] = __builtin_amdgcn_mfma_f32_16x16x32_bf16(a_hi[r], bh, acc[r][g], 0,0,0);
        acc[r][g] = __builtin_amdgcn_mfma_f32_16x16x32_bf16(a_lo[r], bh, acc[r][g], 0,0,0);
        acc[r][g] = __builtin_amdgcn_mfma_f32_16x16x32_bf16(a_hi[r], bl, acc[r][g], 0,0,0);
      }
    }
  }

  ushort4* xb = (ushort4*)(Xp + ((size_t)blk*16 + wn)*2048);
  #pragma unroll
  for (int r=0;r<2;r++)
    #pragma unroll
    for (int g=0;g<4;g++){
      ushort4 xv;
      xv.x = f2bf(acc[r][g][0]); xv.y = f2bf(acc[r][g][1]);
      xv.z = f2bf(acc[r][g][2]); xv.w = f2bf(acc[r][g][3]);
      xb[(r*4+g)*64 + lane] = xv;
    }
}

// ---------------- fused step: gather(s-1) + LSTM/branch(s); 1-term MFMA, bf16 h, bf16 X ----------------
// grid 256 blocks (16 ex x 16 rowblocks of 32), 1024 threads = 16 waves.
__global__ __launch_bounds__(1024) void k_fused(
    const u16* __restrict__ Xp,
    const u16* __restrict__ Wp_hi,
    const float* __restrict__ Wb, const float* __restrict__ bb,
    const int* __restrict__ exit_idx, const int* __restrict__ steps,
    const int* __restrict__ offsets, const int* __restrict__ entries,
    const float* __restrict__ c2r, const u16* __restrict__ h2r,
    const float* __restrict__ ptr_, const float* __restrict__ pfr,
    float* __restrict__ c2w, u16* __restrict__ h2w,
    float* __restrict__ ptw, float* __restrict__ pfw,
    float* __restrict__ exf, int s)
{
  int blk = blockIdx.x;
  int b = blk >> 4;
  int st = steps[b];
  if (s > st) return;
  int row0 = (blk & 15) * 32;
  int tid = threadIdx.x;
  int wn = tid >> 6, lane = tid & 63;
  int lrow = lane & 15, lk = lane >> 4;
  int ch = wn*16 + lrow;
  int eb = exit_idx[b];
  int wo = wn >> 2, jj4 = wn & 3;
  bool fin = (s == st);

  __shared__ u16 hh_lds[32*256];   // bf16 h, XOR-swizzled rows (16 KB)
  __shared__ float c_lds[32][260]; // gathered c, padded stride (33.3 KB)
  __shared__ float ip_lds[32];
  __shared__ float prs[16][32][2];

  // issue X loads early (independent of gather)
  f32x4 acc[2][4];
  if (!fin){
    const ushort4* xb = (const ushort4*)(Xp + ((size_t)blk*16 + wn)*2048);
    #pragma unroll
    for (int r=0;r<2;r++)
      #pragma unroll
      for (int g=0;g<4;g++){
        ushort4 xv = xb[(r*4+g)*64 + lane];
        acc[r][g] = (f32x4){bf2f(xv.x), bf2f(xv.y), bf2f(xv.z), bf2f(xv.w)};
      }
  }

  // ---- Phase A: gather previous step's outputs into LDS (or init at s==0) ----
  if (s == 0){
    for (int i = tid; i < 32*256; i += 1024) hh_lds[i] = 0;
    for (int i = tid; i < 32*260; i += 1024) (&c_lds[0][0])[i] = 0.f;
    if (tid < 32) ip_lds[tid] = (row0 + tid == 0) ? 1.f : 0.f;
  } else {
    const float* c2rb = c2r + (size_t)b*kN*kH;
    const u16*   h2rb = h2r + (size_t)b*kN*kH;
    const int*   ebL  = entries + b*2*kN;
    const int*   offB = offsets + b*(kN+1);
    const float* ptb_ = ptr_ + b*kN;
    const float* pfb_ = pfr  + b*kN;
    #pragma unroll
    for (int mi = 0; mi < 2; ++mi){
      int mloc = wn*2 + mi;
      int m = row0 + mloc;
      if (fin && m != eb) continue;      // final step: only the exit row matters
      int start = offB[m], end = offB[m+1];
      float4 aC = {0.f,0.f,0.f,0.f}, aH = {0.f,0.f,0.f,0.f};
      float aP = 0.f;
      for (int e = start; e < end; e += 4){   // batch-4 pipelined, deterministic order
        int   se[4]; float pv[4];
        #pragma unroll
        for (int q=0;q<4;q++){
          bool ok = (e+q < end);
          int ent = ebL[ok ? e+q : e];
          int src = ent & 0xFFFF;
          float p = (ent>>16) ? pfb_[src] : ptb_[src];
          se[q] = src;
          pv[q] = ok ? p : 0.f;
        }
        float4 cv[4]; ushort4 hv[4];
        #pragma unroll
        for (int q=0;q<4;q++){
          cv[q] = *(const float4*)&c2rb[(size_t)se[q]*kH + lane*4];
          hv[q] = *(const ushort4*)&h2rb[(size_t)se[q]*kH + lane*4];
        }
        #pragma unroll
        for (int q=0;q<4;q++){
          aP += pv[q];
          aC.x += pv[q]*cv[q].x; aC.y += pv[q]*cv[q].y;
          aC.z += pv[q]*cv[q].z; aC.w += pv[q]*cv[q].w;
          aH.x += pv[q]*bf2f(hv[q].x); aH.y += pv[q]*bf2f(hv[q].y);
          aH.z += pv[q]*bf2f(hv[q].z); aH.w += pv[q]*bf2f(hv[q].w);
        }
      }
      float inv = 1.f/(aP + 1e-7f);
      float oc[4] = {aC.x*inv, aC.y*inv, aC.z*inv, aC.w*inv};
      float oh[4] = {aH.x*inv, aH.y*inv, aH.z*inv, aH.w*inv};
      if (fin){
        *(float4*)&exf[b*2*kH + lane*4]      = *(float4*)oc;
        *(float4*)&exf[b*2*kH + kH + lane*4] = *(float4*)oh;
      } else {
        *(float4*)&c_lds[mloc][lane*4] = *(float4*)oc;
        ushort4 hh4;
        u16* hhp = (u16*)&hh4;
        #pragma unroll
        for (int q=0;q<4;q++) hhp[q] = f2bf(oh[q]);
        int bo2 = (mloc*512 + lane*8) ^ ((mloc&7)<<4);
        *(ushort4*)((char*)hh_lds + bo2) = hh4;
        if (lane == 0) ip_lds[mloc] = aP;
      }
    }
  }
  if (fin) return;
  __syncthreads();

  // ---- Phase B: MFMA K-loop (1-term: bf16 h x bf16-hi W), A from swizzled LDS ----
  for (int kt=0; kt<8; ++kt){
    short8v a[2];
    #pragma unroll
    for (int r=0;r<2;r++){
      int row = r*16 + lrow;
      int bo2 = (row*512 + kt*64 + lk*16) ^ ((row&7)<<4);
      a[r] = *(const short8v*)((char*)hh_lds + bo2);
    }
    #pragma unroll
    for (int g=0; g<4; ++g){
      size_t fb = ((size_t)((kt*4+wo)*16 + g*4 + jj4))*512 + (size_t)lane*8;
      short8v bh = *(const short8v*)(Wp_hi+fb);
      #pragma unroll
      for (int r=0;r<2;r++)
        acc[r][g] = __builtin_amdgcn_mfma_f32_16x16x32_bf16(a[r], bh, acc[r][g], 0,0,0);
    }
  }

  // ---- epilogue: gates, exit override, branch-logit partials ----
  float wbc0 = Wb[ch*2+0],      wbc1 = Wb[ch*2+1];
  float wbh0 = Wb[(kH+ch)*2+0], wbh1 = Wb[(kH+ch)*2+1];
  float pr0[8], pr1[8];
  #pragma unroll
  for (int r=0;r<2;r++)
    #pragma unroll
    for (int reg=0;reg<4;reg++){
      int rloc = r*16 + lk*4 + reg;
      int row = row0 + rloc;
      float zi = acc[r][0][reg];
      float zf = acc[r][1][reg];
      float zg = acc[r][2][reg];
      float zo = acc[r][3][reg];
      float cp = c_lds[rloc][ch];
      float c2v = sigm(zf)*cp + sigm(zi)*tanhf(zg);
      float h2v = sigm(zo)*tanhf(c2v);
      if (row == eb){
        int bo2 = (rloc*512 + ch*2) ^ ((rloc&7)<<4);
        c2v = cp;
        h2v = bf2f(*(const u16*)((const char*)hh_lds + bo2));
      }
      size_t gb = ((size_t)b*kN + row)*kH + ch;
      c2w[gb] = c2v;
      h2w[gb] = f2bf(h2v);
      int pi = r*4+reg;
      pr0[pi] = c2v*wbc0 + h2v*wbh0;
      pr1[pi] = c2v*wbc1 + h2v*wbh1;
    }

  #pragma unroll
  for (int off=1; off<16; off<<=1){
    #pragma unroll
    for (int i=0;i<8;i++){
      pr0[i] += __shfl_xor(pr0[i], off);
      pr1[i] += __shfl_xor(pr1[i], off);
    }
  }
  if (lrow == 0){
    #pragma unroll
    for (int r=0;r<2;r++)
      #pragma unroll
      for (int reg=0;reg<4;reg++){
        int lr = r*16 + lk*4 + reg;
        prs[wn][lr][0] = pr0[r*4+reg];
        prs[wn][lr][1] = pr1[r*4+reg];
      }
  }
  __syncthreads();
  if (tid < 32){
    int row = row0 + tid;
    float u0 = bb[0], u1 = bb[1];
    #pragma unroll
    for (int w=0;w<16;w++){ u0 += prs[w][tid][0]; u1 += prs[w][tid][1]; }
    float mx = fmaxf(u0,u1);
    float e0 = expf(u0-mx), e1 = expf(u1-mx);
    float inv = 1.f/(e0+e1);
    float ipv = ip_lds[tid];
    ptw[b*kN+row] = (e0*inv)*ipv;
    pfw[b*kN+row] = (e1*inv)*ipv;
  }
}

// ---------------- final: logits = exitstate @ Wo + bo  (split-K) ----------------
__global__ __launch_bounds__(256) void k_out_part(
    const float* __restrict__ exf, const float* __restrict__ Wo,
    float* __restrict__ partial)
{
  int kq = blockIdx.x / 125;
  int vt = blockIdx.x % 125;
  int t = threadIdx.x;
  __shared__ float sf[kB][128];
  for (int i = t; i < kB*128; i += 256){
    int b = i >> 7; int kl = i & 127;
    sf[b][kl] = exf[b*2*kH + kq*128 + kl];
  }
  __syncthreads();
  int v = vt*256 + t;
  float acc[kB];
  #pragma unroll
  for (int b=0;b<kB;b++) acc[b] = 0.f;
  int k0 = kq*128;
  for (int kl=0; kl<128; kl+=4){
    float w0 = Wo[(size_t)(k0+kl+0)*kV + v];
    float w1 = Wo[(size_t)(k0+kl+1)*kV + v];
    float w2 = Wo[(size_t)(k0+kl+2)*kV + v];
    float w3 = Wo[(size_t)(k0+kl+3)*kV + v];
    #pragma unroll
    for (int b=0;b<kB;b++){
      float4 s4 = *(const float4*)&sf[b][kl];
      acc[b] += s4.x*w0 + s4.y*w1 + s4.z*w2 + s4.w*w3;
    }
  }
  #pragma unroll
  for (int b=0;b<kB;b++) partial[(size_t)(kq*kB+b)*kV + v] = acc[b];
}

__global__ __launch_bounds__(256) void k_out_sum(
    const float* __restrict__ partial, const float* __restrict__ bo,
    float* __restrict__ out)
{
  int v = blockIdx.x*256 + threadIdx.x;
  if (v >= kV) return;
  float bv = bo[v];
  #pragma unroll
  for (int b=0;b<kB;b++){
    float s = bv;
    #pragma unroll
    for (int q=0;q<4;q++) s += partial[(size_t)(q*kB+b)*kV + v];
    out[(size_t)b*kV + v] = s;
  }
}

extern "C" void kernel_launch(void* const* d_in, const int* in_sizes, int n_in,
                              void* d_out, int out_size, void* d_ws, size_t ws_size,
                              hipStream_t stream) {
  const float* emb   = (const float*)d_in[0];
  const float* Wx    = (const float*)d_in[1];
  const float* Wh    = (const float*)d_in[2];
  const float* bias  = (const float*)d_in[3];
  const float* Wb    = (const float*)d_in[4];
  const float* bbias = (const float*)d_in[5];
  const float* Wo    = (const float*)d_in[6];
  const float* bo    = (const float*)d_in[7];
  const int* t_idx   = (const int*)d_in[8];
  const int* f_idx   = (const int*)d_in[9];
  const int* exit_i  = (const int*)d_in[10];
  const int* steps   = (const int*)d_in[11];
  float* out = (float*)d_out;

  char* ws = (char*)d_ws;
  u16* Xp  = (u16*)ws;    ws += (size_t)kB*kN*kH4*2;      // 16.8 MB, bf16 frag-ordered X
  float* c2a = (float*)ws; ws += (size_t)kB*kN*kH*4;      // ping (written at even s)
  float* c2b = (float*)ws; ws += (size_t)kB*kN*kH*4;      // pong (written at odd s)
  u16* h2a = (u16*)ws;    ws += (size_t)kB*kN*kH*2;       // bf16 h state
  u16* h2b = (u16*)ws;    ws += (size_t)kB*kN*kH*2;
  u16* Wp_hi  = (u16*)ws; ws += (size_t)kH*kH4*2;
  u16* Wxp_hi = (u16*)ws; ws += (size_t)kH*kH4*2;
  u16* Wxp_lo = (u16*)ws; ws += (size_t)kH*kH4*2;
  float* pta = (float*)ws; ws += (size_t)kB*kN*4;
  float* pfa = (float*)ws; ws += (size_t)kB*kN*4;
  float* ptb = (float*)ws; ws += (size_t)kB*kN*4;
  float* pfb = (float*)ws; ws += (size_t)kB*kN*4;
  float* exf = (float*)ws; ws += (size_t)kB*2*kH*4;
  int* offsets = (int*)ws; ws += ((size_t)kB*(kN+1)*4 + 255) & ~(size_t)255;
  int* entries = (int*)ws; ws += (size_t)kB*2*kN*4;
  float* partial = (float*)ws; ws += (size_t)4*kB*kV*4;   // 8.2 MB split-K partials

  k_csr<<<kB, kN, 0, stream>>>(t_idx, f_idx, offsets, entries);
  k_pack2<<<1024, 64, 0, stream>>>(Wh, Wx, Wp_hi, Wxp_hi, Wxp_lo);
  k_x_mfma<<<256, 1024, 0, stream>>>(emb, Wxp_hi, Wxp_lo, bias, Xp);

  for (int s = 0; s < kS; ++s){
    bool even = ((s & 1) == 0);
    k_fused<<<256, 1024, 0, stream>>>(
        Xp, Wp_hi, Wb, bbias, exit_i, steps, offsets, entries,
        even ? c2b : c2a, even ? h2b : h2a, even ? ptb : pta, even ? pfb : pfa,  // read (s-1)
        even ? c2a : c2b, even ? h2a : h2b, even ? pta : ptb, even ? pfa : pfb,  // write (s)
        exf, s);
  }

  k_out_part<<<500, 256, 0, stream>>>(exf, Wo, partial);
  k_out_sum<<<125, 256, 0, stream>>>(partial, bo, out);
}

// Round 10
// 821.182 us; speedup vs baseline: 5.0193x; 1.2506x over previous
//
#include <hip/hip_runtime.h>
#include <hip/hip_bf16.h>

constexpr int kB  = 16;     // batch
constexpr int kN  = 512;    // nodes
constexpr int kH  = 256;    // hidden
constexpr int kH4 = 1024;   // 4*H
constexpr int kV  = 32000;  // vocab
constexpr int kS  = 48;     // MAX_STEPS (steps[b] <= 47)

typedef __attribute__((ext_vector_type(8))) short short8v;  // 8 bf16 = 4 VGPR
typedef __attribute__((ext_vector_type(4))) float f32x4;
typedef unsigned short u16;

__device__ __forceinline__ float sigm(float x){ return 1.f/(1.f+expf(-x)); }
// fast variants for the step-loop epilogue (v_exp_f32 + v_rcp_f32; err ~1e-5)
__device__ __forceinline__ float fsigm(float x){
  return __builtin_amdgcn_rcpf(1.f + __expf(-x));
}
__device__ __forceinline__ float ftanh(float x){
  return 1.f - 2.f*__builtin_amdgcn_rcpf(1.f + __expf(2.f*x));
}

__device__ __forceinline__ u16 f2bf(float f){
  __hip_bfloat16 h = __float2bfloat16(f);
  return __builtin_bit_cast(u16, h);
}
__device__ __forceinline__ float bf2f(u16 u){
  __hip_bfloat16 h = __builtin_bit_cast(__hip_bfloat16, u);
  return __bfloat162float(h);
}

// ---------------- CSR build (deterministic): atomics for counts/placement + bucket sort ----------------
__global__ void k_csr(const int* t_idx, const int* f_idx, int* offsets, int* entries){
  int b = blockIdx.x; int t = threadIdx.x; // 512 threads
  __shared__ int tl[kN], fl[kN], cnt[kN], pos[kN], ebuf[2*kN];
  tl[t] = t_idx[b*kN+t]; fl[t] = f_idx[b*kN+t];
  cnt[t] = 0;
  __syncthreads();
  atomicAdd(&cnt[tl[t]], 1);
  atomicAdd(&cnt[fl[t]], 1);
  __syncthreads();
  int myc = cnt[t];
  pos[t] = myc;
  __syncthreads();
  for (int off=1; off<kN; off<<=1){
    int v = pos[t];
    int add = (t>=off)? pos[t-off] : 0;
    __syncthreads();
    pos[t] = v + add;
    __syncthreads();
  }
  int excl = pos[t] - myc;
  offsets[b*(kN+1)+t] = excl;
  if (t==0) offsets[b*(kN+1)+kN] = 2*kN;
  __syncthreads();
  pos[t] = excl;
  __syncthreads();
  int p1 = atomicAdd(&pos[tl[t]], 1); ebuf[p1] = t;            // true branch
  int p2 = atomicAdd(&pos[fl[t]], 1); ebuf[p2] = t | (1<<16);  // false branch
  __syncthreads();
  for (int i = excl+1; i < excl+myc; ++i){      // sort own bucket: reference order
    int v = ebuf[i]; int j = i-1;
    while (j >= excl && ebuf[j] > v){ ebuf[j+1] = ebuf[j]; --j; }
    ebuf[j+1] = v;
  }
  __syncthreads();
  entries[b*2*kN + t]      = ebuf[t];
  entries[b*2*kN + kN + t] = ebuf[kN + t];
}

// ---------------- pack weights into MFMA B-fragment order (hi only) ----------------
// frag fi = ((kt*4 + wo)*16 + (g*4+j)); lane l supplies B[k][col] for
// k = kt*32 + (l>>4)*8 + jj, col = g*256 + wo*64 + j*16 + (l&15)
__global__ void k_pack2(const float* __restrict__ Wh, const float* __restrict__ Wx,
                        u16* __restrict__ Whh, u16* __restrict__ Wxh){
  int id = blockIdx.x; int l = threadIdx.x; // 1024 blocks x 64 threads
  bool isWh = (id < 512);
  const float* W = isWh ? Wh : Wx;
  u16* ph = isWh ? Whh : Wxh;
  int fi = id & 511;
  int kt = fi >> 6; int wo = (fi>>4)&3; int cfl = fi & 15;
  int g = cfl>>2; int j = cfl&3;
  int col = g*kH + wo*64 + j*16 + (l&15);
  int kb = kt*32 + (l>>4)*8;
  size_t o = (size_t)fi*512 + (size_t)l*8;
  #pragma unroll
  for (int jj=0; jj<8; ++jj){
    float w = W[(size_t)(kb+jj)*kH4 + col];
    ph[o+jj] = f2bf(w);
  }
}

// ---------------- X = emb @ Wx + bias (MFMA, 2-term split-A), bf16 frag-order out ----------------
// grid 256 (16 ex x 16 rowblocks of 32), 1024 threads = 16 waves.
__global__ __launch_bounds__(1024) void k_x_mfma(
    const float* __restrict__ emb,
    const u16* __restrict__ Wxp_hi,
    const float* __restrict__ bias, u16* __restrict__ Xp)
{
  int blk = blockIdx.x;
  int b = blk >> 4; int row0 = (blk & 15) * 32;
  int tid = threadIdx.x;
  int wn = tid >> 6, lane = tid & 63;
  int lrow = lane & 15, lk = lane >> 4;
  int ch = wn*16 + lrow;

  f32x4 acc[2][4];
  #pragma unroll
  for (int r=0;r<2;r++)
    #pragma unroll
    for (int g=0;g<4;g++){
      float bv = bias[g*kH + ch];
      acc[r][g] = (f32x4){bv,bv,bv,bv};
    }

  const float* eb_ = emb + ((size_t)b*kN + row0)*kH;
  int wo = wn >> 2, jj4 = wn & 3;
  for (int kt=0; kt<8; ++kt){
    short8v a_hi[2], a_lo[2];
    #pragma unroll
    for (int r=0;r<2;r++){
      size_t off = (size_t)(r*16+lrow)*kH + kt*32 + lk*8;
      float4 v0 = *(const float4*)(eb_ + off);
      float4 v1 = *(const float4*)(eb_ + off + 4);
      float vv[8] = {v0.x,v0.y,v0.z,v0.w,v1.x,v1.y,v1.z,v1.w};
      #pragma unroll
      for (int q=0;q<8;q++){
        u16 hi = f2bf(vv[q]);
        a_hi[r][q] = (short)hi;
        a_lo[r][q] = (short)f2bf(vv[q] - bf2f(hi));
      }
    }
    #pragma unroll
    for (int g=0; g<4; ++g){
      size_t fb = ((size_t)((kt*4+wo)*16 + g*4 + jj4))*512 + (size_t)lane*8;
      short8v bh = *(const short8v*)(Wxp_hi+fb);
      #pragma unroll
      for (int r=0;r<2;r++){
        acc[r][g] = __builtin_amdgcn_mfma_f32_16x16x32_bf16(a_hi[r], bh, acc[r][g], 0,0,0);
        acc[r][g] = __builtin_amdgcn_mfma_f32_16x16x32_bf16(a_lo[r], bh, acc[r][g], 0,0,0);
      }
    }
  }

  ushort4* xb = (ushort4*)(Xp + ((size_t)blk*16 + wn)*2048);
  #pragma unroll
  for (int r=0;r<2;r++)
    #pragma unroll
    for (int g=0;g<4;g++){
      ushort4 xv;
      xv.x = f2bf(acc[r][g][0]); xv.y = f2bf(acc[r][g][1]);
      xv.z = f2bf(acc[r][g][2]); xv.w = f2bf(acc[r][g][3]);
      xb[(r*4+g)*64 + lane] = xv;
    }
}

// ---------------- fused step: gather(s-1) + LSTM/branch(s); 1-term MFMA, bf16 h, bf16 X ----------------
// grid 256 blocks (16 ex x 16 rowblocks of 32), 1024 threads = 16 waves.
__global__ __launch_bounds__(1024) void k_fused(
    const u16* __restrict__ Xp,
    const u16* __restrict__ Wp_hi,
    const float* __restrict__ Wb, const float* __restrict__ bb,
    const int* __restrict__ exit_idx, const int* __restrict__ steps,
    const int* __restrict__ offsets, const int* __restrict__ entries,
    const float* __restrict__ c2r, const u16* __restrict__ h2r,
    const float* __restrict__ ptr_, const float* __restrict__ pfr,
    float* __restrict__ c2w, u16* __restrict__ h2w,
    float* __restrict__ ptw, float* __restrict__ pfw,
    float* __restrict__ exf, int s)
{
  int blk = blockIdx.x;
  int b = blk >> 4;
  int st = steps[b];
  if (s > st) return;
  int row0 = (blk & 15) * 32;
  int tid = threadIdx.x;
  int wn = tid >> 6, lane = tid & 63;
  int lrow = lane & 15, lk = lane >> 4;
  int ch = wn*16 + lrow;
  int eb = exit_idx[b];
  int wo = wn >> 2, jj4 = wn & 3;
  bool fin = (s == st);

  __shared__ u16 hh_lds[32*256];   // bf16 h, XOR-swizzled rows (16 KB)
  __shared__ float c_lds[32][260]; // gathered c, padded stride (33.3 KB)
  __shared__ float ip_lds[32];
  __shared__ float prs[16][32][2];

  // issue X loads early (independent of gather)
  f32x4 acc[2][4];
  if (!fin){
    const ushort4* xb = (const ushort4*)(Xp + ((size_t)blk*16 + wn)*2048);
    #pragma unroll
    for (int r=0;r<2;r++)
      #pragma unroll
      for (int g=0;g<4;g++){
        ushort4 xv = xb[(r*4+g)*64 + lane];
        acc[r][g] = (f32x4){bf2f(xv.x), bf2f(xv.y), bf2f(xv.z), bf2f(xv.w)};
      }
  }

  // ---- Phase A: gather previous step's outputs into LDS (or init at s==0) ----
  if (s == 0){
    for (int i = tid; i < 32*256; i += 1024) hh_lds[i] = 0;
    for (int i = tid; i < 32*260; i += 1024) (&c_lds[0][0])[i] = 0.f;
    if (tid < 32) ip_lds[tid] = (row0 + tid == 0) ? 1.f : 0.f;
  } else {
    const float* c2rb = c2r + (size_t)b*kN*kH;
    const u16*   h2rb = h2r + (size_t)b*kN*kH;
    const int*   ebL  = entries + b*2*kN;
    const int*   offB = offsets + b*(kN+1);
    const float* ptb_ = ptr_ + b*kN;
    const float* pfb_ = pfr  + b*kN;
    #pragma unroll
    for (int mi = 0; mi < 2; ++mi){
      int mloc = wn*2 + mi;
      int m = row0 + mloc;
      if (fin && m != eb) continue;      // final step: only the exit row matters
      int start = offB[m], end = offB[m+1];
      float4 aC = {0.f,0.f,0.f,0.f}, aH = {0.f,0.f,0.f,0.f};
      float aP = 0.f;
      for (int e = start; e < end; e += 4){   // batch-4 pipelined, deterministic order
        int   se[4]; float pv[4];
        #pragma unroll
        for (int q=0;q<4;q++){
          bool ok = (e+q < end);
          int ent = ebL[ok ? e+q : e];
          int src = ent & 0xFFFF;
          float p = (ent>>16) ? pfb_[src] : ptb_[src];
          se[q] = src;
          pv[q] = ok ? p : 0.f;
        }
        float4 cv[4]; ushort4 hv[4];
        #pragma unroll
        for (int q=0;q<4;q++){
          cv[q] = *(const float4*)&c2rb[(size_t)se[q]*kH + lane*4];
          hv[q] = *(const ushort4*)&h2rb[(size_t)se[q]*kH + lane*4];
        }
        #pragma unroll
        for (int q=0;q<4;q++){
          aP += pv[q];
          aC.x += pv[q]*cv[q].x; aC.y += pv[q]*cv[q].y;
          aC.z += pv[q]*cv[q].z; aC.w += pv[q]*cv[q].w;
          aH.x += pv[q]*bf2f(hv[q].x); aH.y += pv[q]*bf2f(hv[q].y);
          aH.z += pv[q]*bf2f(hv[q].z); aH.w += pv[q]*bf2f(hv[q].w);
        }
      }
      float inv = 1.f/(aP + 1e-7f);
      float oc[4] = {aC.x*inv, aC.y*inv, aC.z*inv, aC.w*inv};
      float oh[4] = {aH.x*inv, aH.y*inv, aH.z*inv, aH.w*inv};
      if (fin){
        *(float4*)&exf[b*2*kH + lane*4]      = *(float4*)oc;
        *(float4*)&exf[b*2*kH + kH + lane*4] = *(float4*)oh;
      } else {
        *(float4*)&c_lds[mloc][lane*4] = *(float4*)oc;
        ushort4 hh4;
        u16* hhp = (u16*)&hh4;
        #pragma unroll
        for (int q=0;q<4;q++) hhp[q] = f2bf(oh[q]);
        int bo2 = (mloc*512 + lane*8) ^ ((mloc&7)<<4);
        *(ushort4*)((char*)hh_lds + bo2) = hh4;
        if (lane == 0) ip_lds[mloc] = aP;
      }
    }
  }
  if (fin) return;
  __syncthreads();

  // ---- Phase B: MFMA K-loop (1-term: bf16 h x bf16-hi W), A from swizzled LDS ----
  // s==0: h is identically 0 -> z = X, skip the MFMAs entirely.
  if (s > 0){
    for (int kt=0; kt<8; ++kt){
      short8v a[2];
      #pragma unroll
      for (int r=0;r<2;r++){
        int row = r*16 + lrow;
        int bo2 = (row*512 + kt*64 + lk*16) ^ ((row&7)<<4);
        a[r] = *(const short8v*)((char*)hh_lds + bo2);
      }
      #pragma unroll
      for (int g=0; g<4; ++g){
        size_t fb = ((size_t)((kt*4+wo)*16 + g*4 + jj4))*512 + (size_t)lane*8;
        short8v bh = *(const short8v*)(Wp_hi+fb);
        #pragma unroll
        for (int r=0;r<2;r++)
          acc[r][g] = __builtin_amdgcn_mfma_f32_16x16x32_bf16(a[r], bh, acc[r][g], 0,0,0);
      }
    }
  }

  // ---- epilogue: gates (fast transcendentals), exit override, branch-logit partials ----
  float wbc0 = Wb[ch*2+0],      wbc1 = Wb[ch*2+1];
  float wbh0 = Wb[(kH+ch)*2+0], wbh1 = Wb[(kH+ch)*2+1];
  float pr0[8], pr1[8];
  #pragma unroll
  for (int r=0;r<2;r++)
    #pragma unroll
    for (int reg=0;reg<4;reg++){
      int rloc = r*16 + lk*4 + reg;
      int row = row0 + rloc;
      float zi = acc[r][0][reg];
      float zf = acc[r][1][reg];
      float zg = acc[r][2][reg];
      float zo = acc[r][3][reg];
      float cp = c_lds[rloc][ch];
      float c2v = fsigm(zf)*cp + fsigm(zi)*ftanh(zg);
      float h2v = fsigm(zo)*ftanh(c2v);
      if (row == eb){
        int bo2 = (rloc*512 + ch*2) ^ ((rloc&7)<<4);
        c2v = cp;
        h2v = bf2f(*(const u16*)((const char*)hh_lds + bo2));
      }
      size_t gb = ((size_t)b*kN + row)*kH + ch;
      c2w[gb] = c2v;
      h2w[gb] = f2bf(h2v);
      int pi = r*4+reg;
      pr0[pi] = c2v*wbc0 + h2v*wbh0;
      pr1[pi] = c2v*wbc1 + h2v*wbh1;
    }

  #pragma unroll
  for (int off=1; off<16; off<<=1){
    #pragma unroll
    for (int i=0;i<8;i++){
      pr0[i] += __shfl_xor(pr0[i], off);
      pr1[i] += __shfl_xor(pr1[i], off);
    }
  }
  if (lrow == 0){
    #pragma unroll
    for (int r=0;r<2;r++)
      #pragma unroll
      for (int reg=0;reg<4;reg++){
        int lr = r*16 + lk*4 + reg;
        prs[wn][lr][0] = pr0[r*4+reg];
        prs[wn][lr][1] = pr1[r*4+reg];
      }
  }
  __syncthreads();
  if (tid < 32){
    int row = row0 + tid;
    float u0 = bb[0], u1 = bb[1];
    #pragma unroll
    for (int w=0;w<16;w++){ u0 += prs[w][tid][0]; u1 += prs[w][tid][1]; }
    float mx = fmaxf(u0,u1);
    float e0 = expf(u0-mx), e1 = expf(u1-mx);
    float inv = 1.f/(e0+e1);
    float ipv = ip_lds[tid];
    ptw[b*kN+row] = (e0*inv)*ipv;
    pfw[b*kN+row] = (e1*inv)*ipv;
  }
}

// ---------------- final: logits = exitstate @ Wo + bo  (split-K) ----------------
__global__ __launch_bounds__(256) void k_out_part(
    const float* __restrict__ exf, const float* __restrict__ Wo,
    float* __restrict__ partial)
{
  int kq = blockIdx.x / 125;
  int vt = blockIdx.x % 125;
  int t = threadIdx.x;
  __shared__ float sf[kB][128];
  for (int i = t; i < kB*128; i += 256){
    int b = i >> 7; int kl = i & 127;
    sf[b][kl] = exf[b*2*kH + kq*128 + kl];
  }
  __syncthreads();
  int v = vt*256 + t;
  float acc[kB];
  #pragma unroll
  for (int b=0;b<kB;b++) acc[b] = 0.f;
  int k0 = kq*128;
  for (int kl=0; kl<128; kl+=4){
    float w0 = Wo[(size_t)(k0+kl+0)*kV + v];
    float w1 = Wo[(size_t)(k0+kl+1)*kV + v];
    float w2 = Wo[(size_t)(k0+kl+2)*kV + v];
    float w3 = Wo[(size_t)(k0+kl+3)*kV + v];
    #pragma unroll
    for (int b=0;b<kB;b++){
      float4 s4 = *(const float4*)&sf[b][kl];
      acc[b] += s4.x*w0 + s4.y*w1 + s4.z*w2 + s4.w*w3;
    }
  }
  #pragma unroll
  for (int b=0;b<kB;b++) partial[(size_t)(kq*kB+b)*kV + v] = acc[b];
}

__global__ __launch_bounds__(256) void k_out_sum(
    const float* __restrict__ partial, const float* __restrict__ bo,
    float* __restrict__ out)
{
  int v = blockIdx.x*256 + threadIdx.x;
  if (v >= kV) return;
  float bv = bo[v];
  #pragma unroll
  for (int b=0;b<kB;b++){
    float s = bv;
    #pragma unroll
    for (int q=0;q<4;q++) s += partial[(size_t)(q*kB+b)*kV + v];
    out[(size_t)b*kV + v] = s;
  }
}

extern "C" void kernel_launch(void* const* d_in, const int* in_sizes, int n_in,
                              void* d_out, int out_size, void* d_ws, size_t ws_size,
                              hipStream_t stream) {
  const float* emb   = (const float*)d_in[0];
  const float* Wx    = (const float*)d_in[1];
  const float* Wh    = (const float*)d_in[2];
  const float* bias  = (const float*)d_in[3];
  const float* Wb    = (const float*)d_in[4];
  const float* bbias = (const float*)d_in[5];
  const float* Wo    = (const float*)d_in[6];
  const float* bo    = (const float*)d_in[7];
  const int* t_idx   = (const int*)d_in[8];
  const int* f_idx   = (const int*)d_in[9];
  const int* exit_i  = (const int*)d_in[10];
  const int* steps   = (const int*)d_in[11];
  float* out = (float*)d_out;

  char* ws = (char*)d_ws;
  u16* Xp  = (u16*)ws;    ws += (size_t)kB*kN*kH4*2;      // 16.8 MB, bf16 frag-ordered X
  float* c2a = (float*)ws; ws += (size_t)kB*kN*kH*4;      // ping (written at even s)
  float* c2b = (float*)ws; ws += (size_t)kB*kN*kH*4;      // pong (written at odd s)
  u16* h2a = (u16*)ws;    ws += (size_t)kB*kN*kH*2;       // bf16 h state
  u16* h2b = (u16*)ws;    ws += (size_t)kB*kN*kH*2;
  u16* Wp_hi  = (u16*)ws; ws += (size_t)kH*kH4*2;
  u16* Wxp_hi = (u16*)ws; ws += (size_t)kH*kH4*2;
  float* pta = (float*)ws; ws += (size_t)kB*kN*4;
  float* pfa = (float*)ws; ws += (size_t)kB*kN*4;
  float* ptb = (float*)ws; ws += (size_t)kB*kN*4;
  float* pfb = (float*)ws; ws += (size_t)kB*kN*4;
  float* exf = (float*)ws; ws += (size_t)kB*2*kH*4;
  int* offsets = (int*)ws; ws += ((size_t)kB*(kN+1)*4 + 255) & ~(size_t)255;
  int* entries = (int*)ws; ws += (size_t)kB*2*kN*4;
  float* partial = (float*)ws; ws += (size_t)4*kB*kV*4;   // 8.2 MB split-K partials

  k_csr<<<kB, kN, 0, stream>>>(t_idx, f_idx, offsets, entries);
  k_pack2<<<1024, 64, 0, stream>>>(Wh, Wx, Wp_hi, Wxp_hi);
  k_x_mfma<<<256, 1024, 0, stream>>>(emb, Wxp_hi, bias, Xp);

  for (int s = 0; s < kS; ++s){
    bool even = ((s & 1) == 0);
    k_fused<<<256, 1024, 0, stream>>>(
        Xp, Wp_hi, Wb, bbias, exit_i, steps, offsets, entries,
        even ? c2b : c2a, even ? h2b : h2a, even ? ptb : pta, even ? pfb : pfa,  // read (s-1)
        even ? c2a : c2b, even ? h2a : h2b, even ? pta : ptb, even ? pfa : pfb,  // write (s)
        exf, s);
  }

  k_out_part<<<500, 256, 0, stream>>>(exf, Wo, partial);
  k_out_sum<<<125, 256, 0, stream>>>(partial, bo, out);
}

// Round 11
// 776.579 us; speedup vs baseline: 5.3076x; 1.0574x over previous
//
#include <hip/hip_runtime.h>
#include <hip/hip_bf16.h>

constexpr int kB  = 16;     // batch
constexpr int kN  = 512;    // nodes
constexpr int kH  = 256;    // hidden
constexpr int kH4 = 1024;   // 4*H
constexpr int kV  = 32000;  // vocab
constexpr int kS  = 48;     // MAX_STEPS (steps[b] <= 47)

typedef __attribute__((ext_vector_type(8))) short short8v;  // 8 bf16 = 4 VGPR
typedef __attribute__((ext_vector_type(4))) float f32x4;
typedef unsigned short u16;

__device__ __forceinline__ float sigm(float x){ return 1.f/(1.f+expf(-x)); }
// fast variants for the step-loop epilogue (v_exp_f32 + v_rcp_f32; err ~1e-5)
__device__ __forceinline__ float fsigm(float x){
  return __builtin_amdgcn_rcpf(1.f + __expf(-x));
}
__device__ __forceinline__ float ftanh(float x){
  return 1.f - 2.f*__builtin_amdgcn_rcpf(1.f + __expf(2.f*x));
}

__device__ __forceinline__ u16 f2bf(float f){
  __hip_bfloat16 h = __float2bfloat16(f);
  return __builtin_bit_cast(u16, h);
}
__device__ __forceinline__ float bf2f(u16 u){
  __hip_bfloat16 h = __builtin_bit_cast(__hip_bfloat16, u);
  return __bfloat162float(h);
}

// ---------------- prep: CSR build (blocks 0-15) + weight pack (blocks 16-143) ----------------
// CSR: deterministic via atomics for counts/placement + per-bucket sort (reference order).
// Pack: frag fi = ((kt*4 + wo)*16 + (g*4+j)); lane l supplies B[k][col],
//   k = kt*32 + (l>>4)*8 + jj, col = g*256 + wo*64 + j*16 + (l&15)
__global__ __launch_bounds__(512) void k_prep(
    const int* t_idx, const int* f_idx, int* offsets, int* entries,
    const float* __restrict__ Wh, const float* __restrict__ Wx,
    u16* __restrict__ Whh, u16* __restrict__ Wxh)
{
  __shared__ int tl[kN], fl[kN], cnt[kN], pos[kN], ebuf[2*kN];
  if (blockIdx.x < kB){
    int b = blockIdx.x; int t = threadIdx.x; // 512 threads
    tl[t] = t_idx[b*kN+t]; fl[t] = f_idx[b*kN+t];
    cnt[t] = 0;
    __syncthreads();
    atomicAdd(&cnt[tl[t]], 1);
    atomicAdd(&cnt[fl[t]], 1);
    __syncthreads();
    int myc = cnt[t];
    pos[t] = myc;
    __syncthreads();
    for (int off=1; off<kN; off<<=1){
      int v = pos[t];
      int add = (t>=off)? pos[t-off] : 0;
      __syncthreads();
      pos[t] = v + add;
      __syncthreads();
    }
    int excl = pos[t] - myc;
    offsets[b*(kN+1)+t] = excl;
    if (t==0) offsets[b*(kN+1)+kN] = 2*kN;
    __syncthreads();
    pos[t] = excl;
    __syncthreads();
    int p1 = atomicAdd(&pos[tl[t]], 1); ebuf[p1] = t;            // true branch
    int p2 = atomicAdd(&pos[fl[t]], 1); ebuf[p2] = t | (1<<16);  // false branch
    __syncthreads();
    for (int i = excl+1; i < excl+myc; ++i){      // sort own bucket: reference order
      int v = ebuf[i]; int j = i-1;
      while (j >= excl && ebuf[j] > v){ ebuf[j+1] = ebuf[j]; --j; }
      ebuf[j+1] = v;
    }
    __syncthreads();
    entries[b*2*kN + t]      = ebuf[t];
    entries[b*2*kN + kN + t] = ebuf[kN + t];
  } else {
    int task = (blockIdx.x - kB)*512 + threadIdx.x;  // 128 blocks x 512 = 65536 tasks
    int id = task >> 6; int l = task & 63;           // id = original pack block
    bool isWh = (id < 512);
    const float* W = isWh ? Wh : Wx;
    u16* ph = isWh ? Whh : Wxh;
    int fi = id & 511;
    int kt = fi >> 6; int wo = (fi>>4)&3; int cfl = fi & 15;
    int g = cfl>>2; int j = cfl&3;
    int col = g*kH + wo*64 + j*16 + (l&15);
    int kb = kt*32 + (l>>4)*8;
    size_t o = (size_t)fi*512 + (size_t)l*8;
    #pragma unroll
    for (int jj=0; jj<8; ++jj){
      float w = W[(size_t)(kb+jj)*kH4 + col];
      ph[o+jj] = f2bf(w);
    }
  }
}

// ---------------- X = emb @ Wx + bias (MFMA, 2-term split-A), bf16 frag-order out ----------------
// grid 256; XCD swizzle: b = blk & 15 (all blocks of an example on one XCD).
__global__ __launch_bounds__(1024) void k_x_mfma(
    const float* __restrict__ emb,
    const u16* __restrict__ Wxp_hi,
    const float* __restrict__ bias, u16* __restrict__ Xp)
{
  int blk = blockIdx.x;
  int b = blk & 15; int row0 = (blk >> 4) * 32;
  int tid = threadIdx.x;
  int wn = tid >> 6, lane = tid & 63;
  int lrow = lane & 15, lk = lane >> 4;
  int ch = wn*16 + lrow;

  f32x4 acc[2][4];
  #pragma unroll
  for (int r=0;r<2;r++)
    #pragma unroll
    for (int g=0;g<4;g++){
      float bv = bias[g*kH + ch];
      acc[r][g] = (f32x4){bv,bv,bv,bv};
    }

  const float* eb_ = emb + ((size_t)b*kN + row0)*kH;
  int wo = wn >> 2, jj4 = wn & 3;
  for (int kt=0; kt<8; ++kt){
    short8v a_hi[2], a_lo[2];
    #pragma unroll
    for (int r=0;r<2;r++){
      size_t off = (size_t)(r*16+lrow)*kH + kt*32 + lk*8;
      float4 v0 = *(const float4*)(eb_ + off);
      float4 v1 = *(const float4*)(eb_ + off + 4);
      float vv[8] = {v0.x,v0.y,v0.z,v0.w,v1.x,v1.y,v1.z,v1.w};
      #pragma unroll
      for (int q=0;q<8;q++){
        u16 hi = f2bf(vv[q]);
        a_hi[r][q] = (short)hi;
        a_lo[r][q] = (short)f2bf(vv[q] - bf2f(hi));
      }
    }
    #pragma unroll
    for (int g=0; g<4; ++g){
      size_t fb = ((size_t)((kt*4+wo)*16 + g*4 + jj4))*512 + (size_t)lane*8;
      short8v bh = *(const short8v*)(Wxp_hi+fb);
      #pragma unroll
      for (int r=0;r<2;r++){
        acc[r][g] = __builtin_amdgcn_mfma_f32_16x16x32_bf16(a_hi[r], bh, acc[r][g], 0,0,0);
        acc[r][g] = __builtin_amdgcn_mfma_f32_16x16x32_bf16(a_lo[r], bh, acc[r][g], 0,0,0);
      }
    }
  }

  ushort4* xb = (ushort4*)(Xp + ((size_t)blk*16 + wn)*2048);
  #pragma unroll
  for (int r=0;r<2;r++)
    #pragma unroll
    for (int g=0;g<4;g++){
      ushort4 xv;
      xv.x = f2bf(acc[r][g][0]); xv.y = f2bf(acc[r][g][1]);
      xv.z = f2bf(acc[r][g][2]); xv.w = f2bf(acc[r][g][3]);
      xb[(r*4+g)*64 + lane] = xv;
    }
}

// ---------------- fused step: gather(s-1) + LSTM/branch(s); B-fragment software pipeline ----------------
// grid 256 blocks, 1024 threads = 16 waves; b = blk & 15 (XCD locality).
__global__ __launch_bounds__(1024) void k_fused(
    const u16* __restrict__ Xp,
    const u16* __restrict__ Wp_hi,
    const float* __restrict__ Wb, const float* __restrict__ bb,
    const int* __restrict__ exit_idx, const int* __restrict__ steps,
    const int* __restrict__ offsets, const int* __restrict__ entries,
    const float* __restrict__ c2r, const u16* __restrict__ h2r,
    const float* __restrict__ ptr_, const float* __restrict__ pfr,
    float* __restrict__ c2w, u16* __restrict__ h2w,
    float* __restrict__ ptw, float* __restrict__ pfw,
    float* __restrict__ exf, int s)
{
  int blk = blockIdx.x;
  int b = blk & 15;
  int st = steps[b];
  if (s > st) return;
  int row0 = (blk >> 4) * 32;
  int tid = threadIdx.x;
  int wn = tid >> 6, lane = tid & 63;
  int lrow = lane & 15, lk = lane >> 4;
  int ch = wn*16 + lrow;
  int eb = exit_idx[b];
  int wo = wn >> 2, jj4 = wn & 3;
  bool fin = (s == st);

  __shared__ u16 hh_lds[32*256];   // bf16 h, XOR-swizzled rows (16 KB)
  __shared__ float c_lds[32][260]; // gathered c, padded stride (33.3 KB)
  __shared__ float ip_lds[32];
  __shared__ float prs[16][32][2];

  // per-wave B base pointer (kt stride = 32768 u16, g stride = 2048 u16)
  const u16* bp = Wp_hi + (size_t)wo*8192 + (size_t)jj4*512 + (size_t)lane*8;

  // issue X loads + kt=0 B prefetch early (independent of gather; hidden under Phase A)
  f32x4 acc[2][4];
  short8v bcur[4];
  if (!fin){
    const ushort4* xb = (const ushort4*)(Xp + ((size_t)blk*16 + wn)*2048);
    #pragma unroll
    for (int r=0;r<2;r++)
      #pragma unroll
      for (int g=0;g<4;g++){
        ushort4 xv = xb[(r*4+g)*64 + lane];
        acc[r][g] = (f32x4){bf2f(xv.x), bf2f(xv.y), bf2f(xv.z), bf2f(xv.w)};
      }
    if (s > 0){
      #pragma unroll
      for (int g=0;g<4;g++) bcur[g] = *(const short8v*)(bp + g*2048);
    }
  }

  // ---- Phase A: gather previous step's outputs into LDS (or init at s==0) ----
  if (s == 0){
    for (int i = tid; i < 32*256; i += 1024) hh_lds[i] = 0;
    for (int i = tid; i < 32*260; i += 1024) (&c_lds[0][0])[i] = 0.f;
    if (tid < 32) ip_lds[tid] = (row0 + tid == 0) ? 1.f : 0.f;
  } else {
    const float* c2rb = c2r + (size_t)b*kN*kH;
    const u16*   h2rb = h2r + (size_t)b*kN*kH;
    const int*   ebL  = entries + b*2*kN;
    const int*   offB = offsets + b*(kN+1);
    const float* ptb_ = ptr_ + b*kN;
    const float* pfb_ = pfr  + b*kN;
    #pragma unroll
    for (int mi = 0; mi < 2; ++mi){
      int mloc = wn*2 + mi;
      int m = row0 + mloc;
      if (fin && m != eb) continue;      // final step: only the exit row matters
      int start = offB[m], end = offB[m+1];
      float4 aC = {0.f,0.f,0.f,0.f}, aH = {0.f,0.f,0.f,0.f};
      float aP = 0.f;
      for (int e = start; e < end; e += 4){   // batch-4 pipelined, deterministic order
        int   se[4]; float pv[4];
        #pragma unroll
        for (int q=0;q<4;q++){
          bool ok = (e+q < end);
          int ent = ebL[ok ? e+q : e];
          int src = ent & 0xFFFF;
          float p = (ent>>16) ? pfb_[src] : ptb_[src];
          se[q] = src;
          pv[q] = ok ? p : 0.f;
        }
        float4 cv[4]; ushort4 hv[4];
        #pragma unroll
        for (int q=0;q<4;q++){
          cv[q] = *(const float4*)&c2rb[(size_t)se[q]*kH + lane*4];
          hv[q] = *(const ushort4*)&h2rb[(size_t)se[q]*kH + lane*4];
        }
        #pragma unroll
        for (int q=0;q<4;q++){
          aP += pv[q];
          aC.x += pv[q]*cv[q].x; aC.y += pv[q]*cv[q].y;
          aC.z += pv[q]*cv[q].z; aC.w += pv[q]*cv[q].w;
          aH.x += pv[q]*bf2f(hv[q].x); aH.y += pv[q]*bf2f(hv[q].y);
          aH.z += pv[q]*bf2f(hv[q].z); aH.w += pv[q]*bf2f(hv[q].w);
        }
      }
      float inv = 1.f/(aP + 1e-7f);
      float oc[4] = {aC.x*inv, aC.y*inv, aC.z*inv, aC.w*inv};
      float oh[4] = {aH.x*inv, aH.y*inv, aH.z*inv, aH.w*inv};
      if (fin){
        *(float4*)&exf[b*2*kH + lane*4]      = *(float4*)oc;
        *(float4*)&exf[b*2*kH + kH + lane*4] = *(float4*)oh;
      } else {
        *(float4*)&c_lds[mloc][lane*4] = *(float4*)oc;
        ushort4 hh4;
        u16* hhp = (u16*)&hh4;
        #pragma unroll
        for (int q=0;q<4;q++) hhp[q] = f2bf(oh[q]);
        int bo2 = (mloc*512 + lane*8) ^ ((mloc&7)<<4);
        *(ushort4*)((char*)hh_lds + bo2) = hh4;
        if (lane == 0) ip_lds[mloc] = aP;
      }
    }
  }
  if (fin) return;
  __syncthreads();

  // ---- Phase B: MFMA K-loop (1-term), software-pipelined B loads, A from swizzled LDS ----
  // s==0: h is identically 0 -> z = X, skip the MFMAs entirely.
  if (s > 0){
    #pragma unroll
    for (int kt=0; kt<8; ++kt){
      short8v a[2];
      #pragma unroll
      for (int r=0;r<2;r++){
        int row = r*16 + lrow;
        int bo2 = (row*512 + kt*64 + lk*16) ^ ((row&7)<<4);
        a[r] = *(const short8v*)((char*)hh_lds + bo2);
      }
      short8v bnxt[4];
      {
        int kto = (kt < 7) ? (kt+1)*32768 : 7*32768;  // dummy (in-bounds) on last iter
        #pragma unroll
        for (int g=0;g<4;g++) bnxt[g] = *(const short8v*)(bp + kto + g*2048);
      }
      #pragma unroll
      for (int g=0; g<4; ++g)
        #pragma unroll
        for (int r=0;r<2;r++)
          acc[r][g] = __builtin_amdgcn_mfma_f32_16x16x32_bf16(a[r], bcur[g], acc[r][g], 0,0,0);
      #pragma unroll
      for (int g=0;g<4;g++) bcur[g] = bnxt[g];
    }
  }

  // ---- epilogue: gates (fast transcendentals), exit override, branch-logit partials ----
  float wbc0 = Wb[ch*2+0],      wbc1 = Wb[ch*2+1];
  float wbh0 = Wb[(kH+ch)*2+0], wbh1 = Wb[(kH+ch)*2+1];
  float pr0[8], pr1[8];
  #pragma unroll
  for (int r=0;r<2;r++)
    #pragma unroll
    for (int reg=0;reg<4;reg++){
      int rloc = r*16 + lk*4 + reg;
      int row = row0 + rloc;
      float zi = acc[r][0][reg];
      float zf = acc[r][1][reg];
      float zg = acc[r][2][reg];
      float zo = acc[r][3][reg];
      float cp = c_lds[rloc][ch];
      float c2v = fsigm(zf)*cp + fsigm(zi)*ftanh(zg);
      float h2v = fsigm(zo)*ftanh(c2v);
      if (row == eb){
        int bo2 = (rloc*512 + ch*2) ^ ((rloc&7)<<4);
        c2v = cp;
        h2v = bf2f(*(const u16*)((const char*)hh_lds + bo2));
      }
      size_t gb = ((size_t)b*kN + row)*kH + ch;
      c2w[gb] = c2v;
      h2w[gb] = f2bf(h2v);
      int pi = r*4+reg;
      pr0[pi] = c2v*wbc0 + h2v*wbh0;
      pr1[pi] = c2v*wbc1 + h2v*wbh1;
    }

  #pragma unroll
  for (int off=1; off<16; off<<=1){
    #pragma unroll
    for (int i=0;i<8;i++){
      pr0[i] += __shfl_xor(pr0[i], off);
      pr1[i] += __shfl_xor(pr1[i], off);
    }
  }
  if (lrow == 0){
    #pragma unroll
    for (int r=0;r<2;r++)
      #pragma unroll
      for (int reg=0;reg<4;reg++){
        int lr = r*16 + lk*4 + reg;
        prs[wn][lr][0] = pr0[r*4+reg];
        prs[wn][lr][1] = pr1[r*4+reg];
      }
  }
  __syncthreads();
  if (tid < 32){
    int row = row0 + tid;
    float u0 = bb[0], u1 = bb[1];
    #pragma unroll
    for (int w=0;w<16;w++){ u0 += prs[w][tid][0]; u1 += prs[w][tid][1]; }
    float mx = fmaxf(u0,u1);
    float e0 = expf(u0-mx), e1 = expf(u1-mx);
    float inv = 1.f/(e0+e1);
    float ipv = ip_lds[tid];
    ptw[b*kN+row] = (e0*inv)*ipv;
    pfw[b*kN+row] = (e1*inv)*ipv;
  }
}

// ---------------- final: logits = exitstate @ Wo + bo  (split-K) ----------------
__global__ __launch_bounds__(256) void k_out_part(
    const float* __restrict__ exf, const float* __restrict__ Wo,
    float* __restrict__ partial)
{
  int kq = blockIdx.x / 125;
  int vt = blockIdx.x % 125;
  int t = threadIdx.x;
  __shared__ float sf[kB][128];
  for (int i = t; i < kB*128; i += 256){
    int b = i >> 7; int kl = i & 127;
    sf[b][kl] = exf[b*2*kH + kq*128 + kl];
  }
  __syncthreads();
  int v = vt*256 + t;
  float acc[kB];
  #pragma unroll
  for (int b=0;b<kB;b++) acc[b] = 0.f;
  int k0 = kq*128;
  for (int kl=0; kl<128; kl+=4){
    float w0 = Wo[(size_t)(k0+kl+0)*kV + v];
    float w1 = Wo[(size_t)(k0+kl+1)*kV + v];
    float w2 = Wo[(size_t)(k0+kl+2)*kV + v];
    float w3 = Wo[(size_t)(k0+kl+3)*kV + v];
    #pragma unroll
    for (int b=0;b<kB;b++){
      float4 s4 = *(const float4*)&sf[b][kl];
      acc[b] += s4.x*w0 + s4.y*w1 + s4.z*w2 + s4.w*w3;
    }
  }
  #pragma unroll
  for (int b=0;b<kB;b++) partial[(size_t)(kq*kB+b)*kV + v] = acc[b];
}

__global__ __launch_bounds__(256) void k_out_sum(
    const float* __restrict__ partial, const float* __restrict__ bo,
    float* __restrict__ out)
{
  int v = blockIdx.x*256 + threadIdx.x;
  if (v >= kV) return;
  float bv = bo[v];
  #pragma unroll
  for (int b=0;b<kB;b++){
    float s = bv;
    #pragma unroll
    for (int q=0;q<4;q++) s += partial[(size_t)(q*kB+b)*kV + v];
    out[(size_t)b*kV + v] = s;
  }
}

extern "C" void kernel_launch(void* const* d_in, const int* in_sizes, int n_in,
                              void* d_out, int out_size, void* d_ws, size_t ws_size,
                              hipStream_t stream) {
  const float* emb   = (const float*)d_in[0];
  const float* Wx    = (const float*)d_in[1];
  const float* Wh    = (const float*)d_in[2];
  const float* bias  = (const float*)d_in[3];
  const float* Wb    = (const float*)d_in[4];
  const float* bbias = (const float*)d_in[5];
  const float* Wo    = (const float*)d_in[6];
  const float* bo    = (const float*)d_in[7];
  const int* t_idx   = (const int*)d_in[8];
  const int* f_idx   = (const int*)d_in[9];
  const int* exit_i  = (const int*)d_in[10];
  const int* steps   = (const int*)d_in[11];
  float* out = (float*)d_out;

  char* ws = (char*)d_ws;
  u16* Xp  = (u16*)ws;    ws += (size_t)kB*kN*kH4*2;      // 16.8 MB, bf16 frag-ordered X
  float* c2a = (float*)ws; ws += (size_t)kB*kN*kH*4;      // ping (written at even s)
  float* c2b = (float*)ws; ws += (size_t)kB*kN*kH*4;      // pong (written at odd s)
  u16* h2a = (u16*)ws;    ws += (size_t)kB*kN*kH*2;       // bf16 h state
  u16* h2b = (u16*)ws;    ws += (size_t)kB*kN*kH*2;
  u16* Wp_hi  = (u16*)ws; ws += (size_t)kH*kH4*2;
  u16* Wxp_hi = (u16*)ws; ws += (size_t)kH*kH4*2;
  float* pta = (float*)ws; ws += (size_t)kB*kN*4;
  float* pfa = (float*)ws; ws += (size_t)kB*kN*4;
  float* ptb = (float*)ws; ws += (size_t)kB*kN*4;
  float* pfb = (float*)ws; ws += (size_t)kB*kN*4;
  float* exf = (float*)ws; ws += (size_t)kB*2*kH*4;
  int* offsets = (int*)ws; ws += ((size_t)kB*(kN+1)*4 + 255) & ~(size_t)255;
  int* entries = (int*)ws; ws += (size_t)kB*2*kN*4;
  float* partial = (float*)ws; ws += (size_t)4*kB*kV*4;   // 8.2 MB split-K partials

  k_prep<<<144, 512, 0, stream>>>(t_idx, f_idx, offsets, entries, Wh, Wx, Wp_hi, Wxp_hi);
  k_x_mfma<<<256, 1024, 0, stream>>>(emb, Wxp_hi, bias, Xp);

  for (int s = 0; s < kS; ++s){
    bool even = ((s & 1) == 0);
    k_fused<<<256, 1024, 0, stream>>>(
        Xp, Wp_hi, Wb, bbias, exit_i, steps, offsets, entries,
        even ? c2b : c2a, even ? h2b : h2a, even ? ptb : pta, even ? pfb : pfa,  // read (s-1)
        even ? c2a : c2b, even ? h2a : h2b, even ? pta : ptb, even ? pfa : pfb,  // write (s)
        exf, s);
  }

  k_out_part<<<500, 256, 0, stream>>>(exf, Wo, partial);
  k_out_sum<<<125, 256, 0, stream>>>(partial, bo, out);
}

// Round 12
// 749.913 us; speedup vs baseline: 5.4964x; 1.0356x over previous
//
#include <hip/hip_runtime.h>
#include <hip/hip_bf16.h>

constexpr int kB  = 16;     // batch
constexpr int kN  = 512;    // nodes
constexpr int kH  = 256;    // hidden
constexpr int kH4 = 1024;   // 4*H
constexpr int kV  = 32000;  // vocab
constexpr int kS  = 48;     // MAX_STEPS (steps[b] <= 47)

typedef __attribute__((ext_vector_type(8))) short short8v;  // 8 bf16 = 4 VGPR
typedef __attribute__((ext_vector_type(4))) float f32x4;
typedef unsigned short u16;

// fast transcendentals for the step-loop epilogue (v_exp_f32 + v_rcp_f32; err ~1e-5)
__device__ __forceinline__ float fsigm(float x){
  return __builtin_amdgcn_rcpf(1.f + __expf(-x));
}
__device__ __forceinline__ float ftanh(float x){
  return 1.f - 2.f*__builtin_amdgcn_rcpf(1.f + __expf(2.f*x));
}

__device__ __forceinline__ u16 f2bf(float f){
  __hip_bfloat16 h = __float2bfloat16(f);
  return __builtin_bit_cast(u16, h);
}
__device__ __forceinline__ float bf2f(u16 u){
  __hip_bfloat16 h = __builtin_bit_cast(__hip_bfloat16, u);
  return __bfloat162float(h);
}

// ---------------- prep: CSR build (blocks 0-15) + weight pack (blocks 16-143) ----------------
__global__ __launch_bounds__(512) void k_prep(
    const int* t_idx, const int* f_idx, int* offsets, int* entries,
    const float* __restrict__ Wh, const float* __restrict__ Wx,
    u16* __restrict__ Whh, u16* __restrict__ Wxh)
{
  __shared__ int tl[kN], fl[kN], cnt[kN], pos[kN], ebuf[2*kN];
  if (blockIdx.x < kB){
    int b = blockIdx.x; int t = threadIdx.x; // 512 threads
    tl[t] = t_idx[b*kN+t]; fl[t] = f_idx[b*kN+t];
    cnt[t] = 0;
    __syncthreads();
    atomicAdd(&cnt[tl[t]], 1);
    atomicAdd(&cnt[fl[t]], 1);
    __syncthreads();
    int myc = cnt[t];
    pos[t] = myc;
    __syncthreads();
    for (int off=1; off<kN; off<<=1){
      int v = pos[t];
      int add = (t>=off)? pos[t-off] : 0;
      __syncthreads();
      pos[t] = v + add;
      __syncthreads();
    }
    int excl = pos[t] - myc;
    offsets[b*(kN+1)+t] = excl;
    if (t==0) offsets[b*(kN+1)+kN] = 2*kN;
    __syncthreads();
    pos[t] = excl;
    __syncthreads();
    int p1 = atomicAdd(&pos[tl[t]], 1); ebuf[p1] = t;            // true branch
    int p2 = atomicAdd(&pos[fl[t]], 1); ebuf[p2] = t | (1<<16);  // false branch
    __syncthreads();
    for (int i = excl+1; i < excl+myc; ++i){      // sort own bucket: reference order
      int v = ebuf[i]; int j = i-1;
      while (j >= excl && ebuf[j] > v){ ebuf[j+1] = ebuf[j]; --j; }
      ebuf[j+1] = v;
    }
    __syncthreads();
    entries[b*2*kN + t]      = ebuf[t];
    entries[b*2*kN + kN + t] = ebuf[kN + t];
  } else {
    int task = (blockIdx.x - kB)*512 + threadIdx.x;  // 128 blocks x 512 = 65536 tasks
    int id = task >> 6; int l = task & 63;
    bool isWh = (id < 512);
    const float* W = isWh ? Wh : Wx;
    u16* ph = isWh ? Whh : Wxh;
    int fi = id & 511;
    int kt = fi >> 6; int wo = (fi>>4)&3; int cfl = fi & 15;
    int g = cfl>>2; int j = cfl&3;
    int col = g*kH + wo*64 + j*16 + (l&15);
    int kb = kt*32 + (l>>4)*8;
    size_t o = (size_t)fi*512 + (size_t)l*8;
    #pragma unroll
    for (int jj=0; jj<8; ++jj){
      float w = W[(size_t)(kb+jj)*kH4 + col];
      ph[o+jj] = f2bf(w);
    }
  }
}

// ---------------- step 0: z = emb@Wx + bias (2-term MFMA), write Xp + full epilogue ----------------
// h=c=0 at s=0: no gather, no LDS state; exit override -> c=h=0; ip analytic (node 0 = 1).
__global__ __launch_bounds__(1024) void k_step0(
    const float* __restrict__ emb, const u16* __restrict__ Wxp_hi,
    const float* __restrict__ bias,
    const float* __restrict__ Wb, const float* __restrict__ bb,
    const int* __restrict__ exit_idx,
    u16* __restrict__ Xp, float* __restrict__ c2w, u16* __restrict__ h2w,
    float* __restrict__ ptw, float* __restrict__ pfw)
{
  int blk = blockIdx.x;
  int b = blk & 15; int row0 = (blk >> 4) * 32;
  int tid = threadIdx.x;
  int wn = tid >> 6, lane = tid & 63;
  int lrow = lane & 15, lk = lane >> 4;
  int ch = wn*16 + lrow;
  int eb = exit_idx[b];
  int wo = wn >> 2, jj4 = wn & 3;
  __shared__ float prs[16][32][2];

  f32x4 acc[2][4];
  #pragma unroll
  for (int r=0;r<2;r++)
    #pragma unroll
    for (int g=0;g<4;g++){
      float bv = bias[g*kH + ch];
      acc[r][g] = (f32x4){bv,bv,bv,bv};
    }

  const float* eb_ = emb + ((size_t)b*kN + row0)*kH;
  for (int kt=0; kt<8; ++kt){
    short8v a_hi[2], a_lo[2];
    #pragma unroll
    for (int r=0;r<2;r++){
      size_t off = (size_t)(r*16+lrow)*kH + kt*32 + lk*8;
      float4 v0 = *(const float4*)(eb_ + off);
      float4 v1 = *(const float4*)(eb_ + off + 4);
      float vv[8] = {v0.x,v0.y,v0.z,v0.w,v1.x,v1.y,v1.z,v1.w};
      #pragma unroll
      for (int q=0;q<8;q++){
        u16 hi = f2bf(vv[q]);
        a_hi[r][q] = (short)hi;
        a_lo[r][q] = (short)f2bf(vv[q] - bf2f(hi));
      }
    }
    #pragma unroll
    for (int g=0; g<4; ++g){
      size_t fb = ((size_t)((kt*4+wo)*16 + g*4 + jj4))*512 + (size_t)lane*8;
      short8v bh = *(const short8v*)(Wxp_hi+fb);
      #pragma unroll
      for (int r=0;r<2;r++){
        acc[r][g] = __builtin_amdgcn_mfma_f32_16x16x32_bf16(a_hi[r], bh, acc[r][g], 0,0,0);
        acc[r][g] = __builtin_amdgcn_mfma_f32_16x16x32_bf16(a_lo[r], bh, acc[r][g], 0,0,0);
      }
    }
  }

  // write Xp (bf16, fragment order) for steps 1+
  ushort4* xb = (ushort4*)(Xp + ((size_t)blk*16 + wn)*2048);
  #pragma unroll
  for (int r=0;r<2;r++)
    #pragma unroll
    for (int g=0;g<4;g++){
      ushort4 xv;
      xv.x = f2bf(acc[r][g][0]); xv.y = f2bf(acc[r][g][1]);
      xv.z = f2bf(acc[r][g][2]); xv.w = f2bf(acc[r][g][3]);
      xb[(r*4+g)*64 + lane] = xv;
    }

  // epilogue with cp = 0
  float wbc0 = Wb[ch*2+0],      wbc1 = Wb[ch*2+1];
  float wbh0 = Wb[(kH+ch)*2+0], wbh1 = Wb[(kH+ch)*2+1];
  float pr0[8], pr1[8];
  #pragma unroll
  for (int r=0;r<2;r++)
    #pragma unroll
    for (int reg=0;reg<4;reg++){
      int rloc = r*16 + lk*4 + reg;
      int row = row0 + rloc;
      float zi = acc[r][0][reg];
      float zg = acc[r][2][reg];
      float zo = acc[r][3][reg];
      float c2v = fsigm(zi)*ftanh(zg);
      float h2v = fsigm(zo)*ftanh(c2v);
      if (row == eb){ c2v = 0.f; h2v = 0.f; }
      size_t gb = ((size_t)b*kN + row)*kH + ch;
      c2w[gb] = c2v;
      h2w[gb] = f2bf(h2v);
      int pi = r*4+reg;
      pr0[pi] = c2v*wbc0 + h2v*wbh0;
      pr1[pi] = c2v*wbc1 + h2v*wbh1;
    }

  #pragma unroll
  for (int off=1; off<16; off<<=1){
    #pragma unroll
    for (int i=0;i<8;i++){
      pr0[i] += __shfl_xor(pr0[i], off);
      pr1[i] += __shfl_xor(pr1[i], off);
    }
  }
  if (lrow == 0){
    #pragma unroll
    for (int r=0;r<2;r++)
      #pragma unroll
      for (int reg=0;reg<4;reg++){
        int lr = r*16 + lk*4 + reg;
        prs[wn][lr][0] = pr0[r*4+reg];
        prs[wn][lr][1] = pr1[r*4+reg];
      }
  }
  __syncthreads();
  if (tid < 32){
    int row = row0 + tid;
    float u0 = bb[0], u1 = bb[1];
    #pragma unroll
    for (int w=0;w<16;w++){ u0 += prs[w][tid][0]; u1 += prs[w][tid][1]; }
    float mx = fmaxf(u0,u1);
    float e0 = expf(u0-mx), e1 = expf(u1-mx);
    float inv = 1.f/(e0+e1);
    float ipv = (row == 0) ? 1.f : 0.f;
    ptw[b*kN+row] = (e0*inv)*ipv;
    pfw[b*kN+row] = (e1*inv)*ipv;
  }
}

// ---------------- fused step (s>=1): half-wave gather + 1-term MFMA ----------------
// grid 256 blocks, 1024 threads = 16 waves; b = blk & 15 (XCD locality).
// Phase A: lanes 0-31 gather target wn*2, lanes 32-63 gather wn*2+1 (concurrent latency chains).
__global__ __launch_bounds__(1024) void k_fused(
    const u16* __restrict__ Xp,
    const u16* __restrict__ Wp_hi,
    const float* __restrict__ Wb, const float* __restrict__ bb,
    const int* __restrict__ exit_idx, const int* __restrict__ steps,
    const int* __restrict__ offsets, const int* __restrict__ entries,
    const float* __restrict__ c2r, const u16* __restrict__ h2r,
    const float* __restrict__ ptr_, const float* __restrict__ pfr,
    float* __restrict__ c2w, u16* __restrict__ h2w,
    float* __restrict__ ptw, float* __restrict__ pfw,
    float* __restrict__ exf, int s)
{
  int blk = blockIdx.x;
  int b = blk & 15;
  int st = steps[b];
  if (s > st) return;
  int row0 = (blk >> 4) * 32;
  int tid = threadIdx.x;
  int wn = tid >> 6, lane = tid & 63;
  int lrow = lane & 15, lk = lane >> 4;
  int half = lane >> 5, hl = lane & 31;
  int ch = wn*16 + lrow;
  int eb = exit_idx[b];
  int wo = wn >> 2, jj4 = wn & 3;
  bool fin = (s == st);

  __shared__ u16 hh_lds[32*256];   // bf16 h, XOR-swizzled rows (16 KB)
  __shared__ float c_lds[32][260]; // gathered c, padded stride (33.3 KB)
  __shared__ float ip_lds[32];
  __shared__ float prs[16][32][2];

  const u16* bp = Wp_hi + (size_t)wo*8192 + (size_t)jj4*512 + (size_t)lane*8;

  // ---- Phase A: half-wave gather of previous step's outputs ----
  {
    int mloc = wn*2 + half;
    int m = row0 + mloc;
    bool skip = fin && (m != eb);
    if (!skip){
      const float* c2rb = c2r + (size_t)b*kN*kH;
      const u16*   h2rb = h2r + (size_t)b*kN*kH;
      const int*   ebL  = entries + b*2*kN;
      const float* ptb_ = ptr_ + b*kN;
      const float* pfb_ = pfr  + b*kN;
      int start = offsets[b*(kN+1)+m], end = offsets[b*(kN+1)+m+1];
      int ch8 = hl*8;
      float aC[8] = {0.f,0.f,0.f,0.f,0.f,0.f,0.f,0.f};
      float aH[8] = {0.f,0.f,0.f,0.f,0.f,0.f,0.f,0.f};
      float aP = 0.f;
      for (int e = start; e < end; e += 4){   // batch-4 pipelined, deterministic order
        int se[4]; float pv[4];
        #pragma unroll
        for (int q=0;q<4;q++){
          bool ok = (e+q < end);
          int ent = ebL[ok ? e+q : e];
          int src = ent & 0xFFFF;
          float p = (ent>>16) ? pfb_[src] : ptb_[src];
          se[q] = src;
          pv[q] = ok ? p : 0.f;
        }
        float4 cv0[4], cv1[4]; short8v hv[4];
        #pragma unroll
        for (int q=0;q<4;q++){
          const float* cb = &c2rb[(size_t)se[q]*kH + ch8];
          cv0[q] = *(const float4*)cb;
          cv1[q] = *(const float4*)(cb+4);
          hv[q]  = *(const short8v*)&h2rb[(size_t)se[q]*kH + ch8];
        }
        #pragma unroll
        for (int q=0;q<4;q++){
          aP += pv[q];
          aC[0]+=pv[q]*cv0[q].x; aC[1]+=pv[q]*cv0[q].y;
          aC[2]+=pv[q]*cv0[q].z; aC[3]+=pv[q]*cv0[q].w;
          aC[4]+=pv[q]*cv1[q].x; aC[5]+=pv[q]*cv1[q].y;
          aC[6]+=pv[q]*cv1[q].z; aC[7]+=pv[q]*cv1[q].w;
          #pragma unroll
          for (int j=0;j<8;j++) aH[j] += pv[q]*bf2f((u16)hv[q][j]);
        }
      }
      float inv = 1.f/(aP + 1e-7f);
      float oc[8], oh[8];
      #pragma unroll
      for (int j=0;j<8;j++){ oc[j]=aC[j]*inv; oh[j]=aH[j]*inv; }
      if (fin){
        float* ex = exf + b*2*kH;
        *(float4*)&ex[ch8]      = *(float4*)&oc[0];
        *(float4*)&ex[ch8+4]    = *(float4*)&oc[4];
        *(float4*)&ex[kH+ch8]   = *(float4*)&oh[0];
        *(float4*)&ex[kH+ch8+4] = *(float4*)&oh[4];
      } else {
        *(float4*)&c_lds[mloc][ch8]   = *(float4*)&oc[0];
        *(float4*)&c_lds[mloc][ch8+4] = *(float4*)&oc[4];
        short8v hh8;
        #pragma unroll
        for (int j=0;j<8;j++) hh8[j] = (short)f2bf(oh[j]);
        int bo2 = (mloc*512 + hl*16) ^ ((mloc&7)<<4);
        *(short8v*)((char*)hh_lds + bo2) = hh8;
        if (hl == 0) ip_lds[mloc] = aP;
      }
    }
  }
  if (fin) return;

  // X loads + kt=0 B prefetch: issued here so they are in flight across the barrier
  f32x4 acc[2][4];
  {
    const ushort4* xb = (const ushort4*)(Xp + ((size_t)blk*16 + wn)*2048);
    #pragma unroll
    for (int r=0;r<2;r++)
      #pragma unroll
      for (int g=0;g<4;g++){
        ushort4 xv = xb[(r*4+g)*64 + lane];
        acc[r][g] = (f32x4){bf2f(xv.x), bf2f(xv.y), bf2f(xv.z), bf2f(xv.w)};
      }
  }
  short8v bcur[4];
  #pragma unroll
  for (int g=0;g<4;g++) bcur[g] = *(const short8v*)(bp + g*2048);
  __syncthreads();

  // ---- Phase B: MFMA K-loop (1-term), software-pipelined B loads, A from swizzled LDS ----
  #pragma unroll
  for (int kt=0; kt<8; ++kt){
    short8v a[2];
    #pragma unroll
    for (int r=0;r<2;r++){
      int row = r*16 + lrow;
      int bo2 = (row*512 + kt*64 + lk*16) ^ ((row&7)<<4);
      a[r] = *(const short8v*)((char*)hh_lds + bo2);
    }
    short8v bnxt[4];
    {
      int kto = (kt < 7) ? (kt+1)*32768 : 7*32768;  // dummy (in-bounds) on last iter
      #pragma unroll
      for (int g=0;g<4;g++) bnxt[g] = *(const short8v*)(bp + kto + g*2048);
    }
    #pragma unroll
    for (int g=0; g<4; ++g)
      #pragma unroll
      for (int r=0;r<2;r++)
        acc[r][g] = __builtin_amdgcn_mfma_f32_16x16x32_bf16(a[r], bcur[g], acc[r][g], 0,0,0);
    #pragma unroll
    for (int g=0;g<4;g++) bcur[g] = bnxt[g];
  }

  // ---- epilogue: gates (fast transcendentals), exit override, branch-logit partials ----
  float wbc0 = Wb[ch*2+0],      wbc1 = Wb[ch*2+1];
  float wbh0 = Wb[(kH+ch)*2+0], wbh1 = Wb[(kH+ch)*2+1];
  float pr0[8], pr1[8];
  #pragma unroll
  for (int r=0;r<2;r++)
    #pragma unroll
    for (int reg=0;reg<4;reg++){
      int rloc = r*16 + lk*4 + reg;
      int row = row0 + rloc;
      float zi = acc[r][0][reg];
      float zf = acc[r][1][reg];
      float zg = acc[r][2][reg];
      float zo = acc[r][3][reg];
      float cp = c_lds[rloc][ch];
      float c2v = fsigm(zf)*cp + fsigm(zi)*ftanh(zg);
      float h2v = fsigm(zo)*ftanh(c2v);
      if (row == eb){
        int bo2 = (rloc*512 + ch*2) ^ ((rloc&7)<<4);
        c2v = cp;
        h2v = bf2f(*(const u16*)((const char*)hh_lds + bo2));
      }
      size_t gb = ((size_t)b*kN + row)*kH + ch;
      c2w[gb] = c2v;
      h2w[gb] = f2bf(h2v);
      int pi = r*4+reg;
      pr0[pi] = c2v*wbc0 + h2v*wbh0;
      pr1[pi] = c2v*wbc1 + h2v*wbh1;
    }

  #pragma unroll
  for (int off=1; off<16; off<<=1){
    #pragma unroll
    for (int i=0;i<8;i++){
      pr0[i] += __shfl_xor(pr0[i], off);
      pr1[i] += __shfl_xor(pr1[i], off);
    }
  }
  if (lrow == 0){
    #pragma unroll
    for (int r=0;r<2;r++)
      #pragma unroll
      for (int reg=0;reg<4;reg++){
        int lr = r*16 + lk*4 + reg;
        prs[wn][lr][0] = pr0[r*4+reg];
        prs[wn][lr][1] = pr1[r*4+reg];
      }
  }
  __syncthreads();
  if (tid < 32){
    int row = row0 + tid;
    float u0 = bb[0], u1 = bb[1];
    #pragma unroll
    for (int w=0;w<16;w++){ u0 += prs[w][tid][0]; u1 += prs[w][tid][1]; }
    float mx = fmaxf(u0,u1);
    float e0 = expf(u0-mx), e1 = expf(u1-mx);
    float inv = 1.f/(e0+e1);
    float ipv = ip_lds[tid];
    ptw[b*kN+row] = (e0*inv)*ipv;
    pfw[b*kN+row] = (e1*inv)*ipv;
  }
}

// ---------------- final: logits = exitstate @ Wo + bo  (split-K) ----------------
__global__ __launch_bounds__(256) void k_out_part(
    const float* __restrict__ exf, const float* __restrict__ Wo,
    float* __restrict__ partial)
{
  int kq = blockIdx.x / 125;
  int vt = blockIdx.x % 125;
  int t = threadIdx.x;
  __shared__ float sf[kB][128];
  for (int i = t; i < kB*128; i += 256){
    int b = i >> 7; int kl = i & 127;
    sf[b][kl] = exf[b*2*kH + kq*128 + kl];
  }
  __syncthreads();
  int v = vt*256 + t;
  float acc[kB];
  #pragma unroll
  for (int b=0;b<kB;b++) acc[b] = 0.f;
  int k0 = kq*128;
  for (int kl=0; kl<128; kl+=4){
    float w0 = Wo[(size_t)(k0+kl+0)*kV + v];
    float w1 = Wo[(size_t)(k0+kl+1)*kV + v];
    float w2 = Wo[(size_t)(k0+kl+2)*kV + v];
    float w3 = Wo[(size_t)(k0+kl+3)*kV + v];
    #pragma unroll
    for (int b=0;b<kB;b++){
      float4 s4 = *(const float4*)&sf[b][kl];
      acc[b] += s4.x*w0 + s4.y*w1 + s4.z*w2 + s4.w*w3;
    }
  }
  #pragma unroll
  for (int b=0;b<kB;b++) partial[(size_t)(kq*kB+b)*kV + v] = acc[b];
}

__global__ __launch_bounds__(256) void k_out_sum(
    const float* __restrict__ partial, const float* __restrict__ bo,
    float* __restrict__ out)
{
  int v = blockIdx.x*256 + threadIdx.x;
  if (v >= kV) return;
  float bv = bo[v];
  #pragma unroll
  for (int b=0;b<kB;b++){
    float s = bv;
    #pragma unroll
    for (int q=0;q<4;q++) s += partial[(size_t)(q*kB+b)*kV + v];
    out[(size_t)b*kV + v] = s;
  }
}

extern "C" void kernel_launch(void* const* d_in, const int* in_sizes, int n_in,
                              void* d_out, int out_size, void* d_ws, size_t ws_size,
                              hipStream_t stream) {
  const float* emb   = (const float*)d_in[0];
  const float* Wx    = (const float*)d_in[1];
  const float* Wh    = (const float*)d_in[2];
  const float* bias  = (const float*)d_in[3];
  const float* Wb    = (const float*)d_in[4];
  const float* bbias = (const float*)d_in[5];
  const float* Wo    = (const float*)d_in[6];
  const float* bo    = (const float*)d_in[7];
  const int* t_idx   = (const int*)d_in[8];
  const int* f_idx   = (const int*)d_in[9];
  const int* exit_i  = (const int*)d_in[10];
  const int* steps   = (const int*)d_in[11];
  float* out = (float*)d_out;

  char* ws = (char*)d_ws;
  u16* Xp  = (u16*)ws;    ws += (size_t)kB*kN*kH4*2;      // 16.8 MB, bf16 frag-ordered X
  float* c2a = (float*)ws; ws += (size_t)kB*kN*kH*4;      // ping (written at even s)
  float* c2b = (float*)ws; ws += (size_t)kB*kN*kH*4;      // pong (written at odd s)
  u16* h2a = (u16*)ws;    ws += (size_t)kB*kN*kH*2;       // bf16 h state
  u16* h2b = (u16*)ws;    ws += (size_t)kB*kN*kH*2;
  u16* Wp_hi  = (u16*)ws; ws += (size_t)kH*kH4*2;
  u16* Wxp_hi = (u16*)ws; ws += (size_t)kH*kH4*2;
  float* pta = (float*)ws; ws += (size_t)kB*kN*4;
  float* pfa = (float*)ws; ws += (size_t)kB*kN*4;
  float* ptb = (float*)ws; ws += (size_t)kB*kN*4;
  float* pfb = (float*)ws; ws += (size_t)kB*kN*4;
  float* exf = (float*)ws; ws += (size_t)kB*2*kH*4;
  int* offsets = (int*)ws; ws += ((size_t)kB*(kN+1)*4 + 255) & ~(size_t)255;
  int* entries = (int*)ws; ws += (size_t)kB*2*kN*4;
  float* partial = (float*)ws; ws += (size_t)4*kB*kV*4;   // 8.2 MB split-K partials

  k_prep<<<144, 512, 0, stream>>>(t_idx, f_idx, offsets, entries, Wh, Wx, Wp_hi, Wxp_hi);
  // step 0: X-GEMM + epilogue fused (writes ping set)
  k_step0<<<256, 1024, 0, stream>>>(emb, Wxp_hi, bias, Wb, bbias, exit_i,
                                    Xp, c2a, h2a, pta, pfa);

  for (int s = 1; s < kS; ++s){
    bool even = ((s & 1) == 0);
    k_fused<<<256, 1024, 0, stream>>>(
        Xp, Wp_hi, Wb, bbias, exit_i, steps, offsets, entries,
        even ? c2b : c2a, even ? h2b : h2a, even ? ptb : pta, even ? pfb : pfa,  // read (s-1)
        even ? c2a : c2b, even ? h2a : h2b, even ? pta : ptb, even ? pfa : pfb,  // write (s)
        exf, s);
  }

  k_out_part<<<500, 256, 0, stream>>>(exf, Wo, partial);
  k_out_sum<<<125, 256, 0, stream>>>(partial, bo, out);
}